// Round 12
// baseline (223.376 us; speedup 1.0000x reference)
//
#include <hip/hip_runtime.h>
#include <math.h>

#define Bb 16
#define Tt 64
#define Nn 64
#define Ss 4
#define Dd 128
#define Hh 8
#define HD 16
#define BN 1024
#define G3 384   // 3*D
#define TT 8     // t-chunk for k_attn

// workspace layout (in floats)
#define OFF_WX   0                              // 4*384
#define OFF_BX   1536                           // 384
#define OFF_YS   4096                           // T*BN*D
#define OFF_KH   (OFF_YS + Tt*BN*Dd)            // f16 [b,h][t][n][16]: 4.19M floats
#define OFF_QH   (OFF_KH + Bb*Hh*Tt*Nn*HD/2)
#define OFF_VW1  (OFF_QH + Bb*Hh*Tt*Nn*HD/2)    // f32 [b,h][t][n]
#define OFF_VW2  (OFF_VW1 + Bb*Hh*Tt*Nn)
#define OFF_E    (OFF_VW2 + Bb*Hh*Tt*Nn)        // B*N*N
#define OFF_VV   (OFF_E + Bb*Nn*Nn)             // BN*D
#define OFF_WKQ  (OFF_VV + BN*Dd)               // f16 frag [W_kc|W_qc|u]: 17408 floats
#define OFF_WT   (OFF_WKQ + 17408)              // f16 frag W_hh: 24576 floats
#define WS_FLOATS (OFF_WT + 24576)

typedef _Float16 half2_t __attribute__((ext_vector_type(2)));
typedef _Float16 f16x8 __attribute__((ext_vector_type(8)));
typedef float f32x4 __attribute__((ext_vector_type(4)));

__device__ __forceinline__ float fast_sigmoid(float v) {
  return 1.f / (1.f + __expf(-v));
}
__device__ __forceinline__ float fast_tanh(float v) {
  float e2 = __expf(2.f * v);
  return 1.f - 2.f / (e2 + 1.f);
}
__device__ __forceinline__ float fdot2(uint32_t a, uint32_t b, float c) {
  half2_t av = __builtin_bit_cast(half2_t, a);
  half2_t bv = __builtin_bit_cast(half2_t, b);
#if __has_builtin(__builtin_amdgcn_fdot2)
  return __builtin_amdgcn_fdot2(av, bv, c, false);
#else
  return c + (float)av.x * (float)bv.x + (float)av.y * (float)bv.y;
#endif
}
__device__ __forceinline__ uint32_t bcast_lane(uint32_t v, int l) {
  return (uint32_t)__builtin_amdgcn_readlane((int)v, l);
}

// ---------------- kernel 0: fold weights + pack W_hh / W_kq / u fragments ----------------
__global__ __launch_bounds__(384) void k_precompute(
    const float* __restrict__ W_se, const float* __restrict__ b_se,
    const float* __restrict__ W_ih, const float* __restrict__ b_ih,
    const float* __restrict__ W_hh,
    const float* __restrict__ W_kc, const float* __restrict__ W_qc,
    const float* __restrict__ W_vc, const float* __restrict__ W_att,
    float* __restrict__ ws) {
  const int tid = threadIdx.x;
  if (blockIdx.x >= 25) {
    const int nt = blockIdx.x - 25;  // 0..16
    _Float16* WF = (_Float16*)(ws + OFF_WKQ);
    for (int idx = tid; idx < 4*64*8; idx += 384) {
      int ks = idx >> 9, l = (idx >> 3) & 63, j = idx & 7;
      int k = ks*32 + (l >> 4)*8 + j;
      int c16 = l & 15;
      float v;
      if (nt < 16) {
        int cg = nt*16 + c16;
        v = (cg < Dd) ? W_kc[(size_t)k*Dd + cg] : W_qc[(size_t)k*Dd + cg - Dd];
      } else {
        int h = c16 >> 1, which = c16 & 1;
        float s = 0.f;
        for (int d = 0; d < HD; ++d)
          s = fmaf(W_vc[(size_t)k*Dd + h*HD + d], W_att[which*Dd + h*HD + d], s);
        v = s;
      }
      WF[(size_t)((nt*4 + ks)*64 + l)*8 + j] = (_Float16)v;
    }
    return;
  }
  if (blockIdx.x > 0) {
    const int nt = blockIdx.x - 1;  // 0..23
    _Float16* WF = (_Float16*)(ws + OFF_WT);
    for (int idx = tid; idx < 4*64*8; idx += 384) {
      int ks = idx >> 9, l = (idx >> 3) & 63, j = idx & 7;
      int k = ks*32 + (l >> 4)*8 + j;
      int c = nt*16 + (l & 15);
      WF[(size_t)((nt*4 + ks)*64 + l)*8 + j] = (_Float16)W_hh[(size_t)k*G3 + c];
    }
    return;
  }
  const int c = tid;
  float* Wx = ws + OFF_WX; float* bx = ws + OFF_BX;
  float accb = b_ih[c];
  float a0 = 0.f, a1 = 0.f, a2 = 0.f, a3 = 0.f;
  for (int k = 0; k < Dd; ++k) {
    float w = W_ih[k*G3 + c];
    accb = fmaf(b_se[k], w, accb);
    a0 = fmaf(W_se[0*Dd + k], w, a0);
    a1 = fmaf(W_se[1*Dd + k], w, a1);
    a2 = fmaf(W_se[2*Dd + k], w, a2);
    a3 = fmaf(W_se[3*Dd + k], w, a3);
  }
  bx[c] = accb;
  Wx[0*G3 + c] = a0; Wx[1*G3 + c] = a1; Wx[2*G3 + c] = a2; Wx[3*G3 + c] = a3;
}

// ---------------- kernel 1: GRU via MFMA (f16), W fragments register-resident ----------------
__global__ __launch_bounds__(512, 2) void k_gru(
    const float* __restrict__ x, const float* __restrict__ W_init,
    const float* __restrict__ b_init,
    const float* __restrict__ b_hh, float* __restrict__ ws) {
  __shared__ __align__(16) _Float16 h_l[4][Dd + 8];
  __shared__ float gg[4][G3];
  __shared__ float xt_l[Tt+1][4][Ss];
  const int tid = threadIdx.x;
  const int wave = tid >> 6;
  const int lane = tid & 63;
  const int l15 = lane & 15;
  const int lk = lane >> 4;
  const int blk = blockIdx.x;
  const int row0 = blk * 4;
  const int b = row0 >> 6;
  const int n0 = row0 & 63;
  float* ys = ws + OFF_YS;
  const float* Wx = ws + OFF_WX;
  const float* bxp = ws + OFF_BX;

  const f16x8* WF = (const f16x8*)(ws + OFF_WT);
  f16x8 wf[3][4];
  #pragma unroll
  for (int i = 0; i < 3; ++i)
    #pragma unroll
    for (int ks = 0; ks < 4; ++ks)
      wf[i][ks] = WF[(size_t)((wave*3 + i)*4 + ks)*64 + lane];
  float br[3];
  #pragma unroll
  for (int i = 0; i < 3; ++i) br[i] = b_hh[(wave*3 + i)*16 + l15];

  const int row = tid >> 7, d = tid & 127;
  float wxr[3][4], bx3[3];
  #pragma unroll
  for (int g = 0; g < 3; ++g) {
    bx3[g] = bxp[g*Dd + d];
    #pragma unroll
    for (int s = 0; s < 4; ++s) wxr[g][s] = Wx[s*G3 + g*Dd + d];
  }

  for (int idx = tid; idx < (Tt+1)*4*Ss; idx += 512) {
    int t = idx >> 4, r = (idx >> 2) & 3, s = idx & 3;
    xt_l[t][r][s] = x[((size_t)(b*(Tt+1) + t)*Nn + (n0 + r))*Ss + s];
  }
  __syncthreads();

  float hprev;
  {
    float h0 = b_init[d];
    #pragma unroll
    for (int s = 0; s < Ss; ++s)
      h0 = fmaf(xt_l[0][row][s], W_init[s*Dd + d], h0);
    hprev = h0;
    h_l[row][d] = (_Float16)h0;
  }
  __syncthreads();

  for (int t = 0; t < Tt; ++t) {
    f16x8 af[4];
    #pragma unroll
    for (int ks = 0; ks < 4; ++ks)
      af[ks] = *(const f16x8*)&h_l[l15 & 3][ks*32 + lk*8];
    #pragma unroll
    for (int i = 0; i < 3; ++i) {
      f32x4 acc = {br[i], br[i], br[i], br[i]};
      #pragma unroll
      for (int ks = 0; ks < 4; ++ks)
        acc = __builtin_amdgcn_mfma_f32_16x16x32_f16(af[ks], wf[i][ks], acc, 0, 0, 0);
      if (lane < 16) {
        const int col = (wave*3 + i)*16 + l15;
        gg[0][col] = acc[0];
        gg[1][col] = acc[1];
        gg[2][col] = acc[2];
        gg[3][col] = acc[3];
      }
    }
    __syncthreads();
    {
      float gi_r = bx3[0], gi_z = bx3[1], gi_n = bx3[2];
      #pragma unroll
      for (int s = 0; s < 4; ++s) {
        float xv = xt_l[t][row][s];
        gi_r = fmaf(xv, wxr[0][s], gi_r);
        gi_z = fmaf(xv, wxr[1][s], gi_z);
        gi_n = fmaf(xv, wxr[2][s], gi_n);
      }
      float rg = fast_sigmoid(gi_r + gg[row][d]);
      float zg = fast_sigmoid(gi_z + gg[row][Dd + d]);
      float ng = fast_tanh(fmaf(rg, gg[row][2*Dd + d], gi_n));
      float hnew = fmaf(zg, hprev - ng, ng);
      hprev = hnew;
      h_l[row][d] = (_Float16)hnew;
      ys[(size_t)(t*BN + row0 + row)*Dd + d] = hnew;
    }
    __syncthreads();
  }
}

// ---------------- kernel 2: k,q,vw via MFMA (f16); K/Q written f16 head-major ----------------
__global__ __launch_bounds__(256, 2) void k_kqv(float* __restrict__ ws) {
  __shared__ __align__(16) _Float16 ysl[64][136];
  const int tid = threadIdx.x;
  const int blk = blockIdx.x;    // b*T + t
  const int b = blk >> 6, t = blk & 63;
  const int wave = tid >> 6, lane = tid & 63;
  const int l15 = lane & 15, lk = lane >> 4;

  const f16x8* WKQ = (const f16x8*)(ws + OFF_WKQ);
  f16x8 bf0[4], bf1[4], bf2[4], bf3[4], bu[4];
  #pragma unroll
  for (int ks = 0; ks < 4; ++ks) {
    bf0[ks] = WKQ[(size_t)((wave*4 + 0)*4 + ks)*64 + lane];
    bf1[ks] = WKQ[(size_t)((wave*4 + 1)*4 + ks)*64 + lane];
    bf2[ks] = WKQ[(size_t)((wave*4 + 2)*4 + ks)*64 + lane];
    bf3[ks] = WKQ[(size_t)((wave*4 + 3)*4 + ks)*64 + lane];
    bu[ks]  = WKQ[(size_t)(16*4 + ks)*64 + lane];
  }

  const float* ysrc = ws + OFF_YS + ((size_t)t*BN + b*64)*Dd;
  for (int idx = tid; idx < 64*16; idx += 256) {
    int r = idx >> 4, k8 = (idx & 15) * 8;
    float4 v0 = *(const float4*)&ysrc[r*Dd + k8];
    float4 v1 = *(const float4*)&ysrc[r*Dd + k8 + 4];
    f16x8 hv;
    hv[0] = (_Float16)v0.x; hv[1] = (_Float16)v0.y;
    hv[2] = (_Float16)v0.z; hv[3] = (_Float16)v0.w;
    hv[4] = (_Float16)v1.x; hv[5] = (_Float16)v1.y;
    hv[6] = (_Float16)v1.z; hv[7] = (_Float16)v1.w;
    *(f16x8*)&ysl[r][k8] = hv;
  }
  __syncthreads();

  _Float16* khd = (_Float16*)(ws + OFF_KH);
  _Float16* qhd = (_Float16*)(ws + OFF_QH);

  #pragma unroll
  for (int mt = 0; mt < 4; ++mt) {
    f16x8 af[4];
    #pragma unroll
    for (int ks = 0; ks < 4; ++ks)
      af[ks] = *(const f16x8*)&ysl[mt*16 + l15][ks*32 + lk*8];
    f32x4 a0 = {0.f,0.f,0.f,0.f}, a1 = a0, a2 = a0, a3 = a0;
    #pragma unroll
    for (int ks = 0; ks < 4; ++ks) {
      a0 = __builtin_amdgcn_mfma_f32_16x16x32_f16(af[ks], bf0[ks], a0, 0, 0, 0);
      a1 = __builtin_amdgcn_mfma_f32_16x16x32_f16(af[ks], bf1[ks], a1, 0, 0, 0);
      a2 = __builtin_amdgcn_mfma_f32_16x16x32_f16(af[ks], bf2[ks], a2, 0, 0, 0);
      a3 = __builtin_amdgcn_mfma_f32_16x16x32_f16(af[ks], bf3[ks], a3, 0, 0, 0);
    }
    const int rowb = mt*16 + lk*4;
    #pragma unroll
    for (int nti = 0; nti < 4; ++nti) {
      f32x4 av = (nti == 0) ? a0 : (nti == 1) ? a1 : (nti == 2) ? a2 : a3;
      const int gc = wave*64 + nti*16 + l15;
      const int hh = (gc >> 4) & 7;
      const int dd2 = gc & 15;
      _Float16* base = (gc < Dd) ? khd : qhd;
      const size_t rowbase = ((size_t)(b*Hh + hh)*Tt + t)*Nn*HD;
      #pragma unroll
      for (int rg2 = 0; rg2 < 4; ++rg2)
        base[rowbase + (size_t)(rowb + rg2)*HD + dd2] = (_Float16)av[rg2];
    }
    if (wave == 3) {
      f32x4 au = {0.f,0.f,0.f,0.f};
      #pragma unroll
      for (int ks = 0; ks < 4; ++ks)
        au = __builtin_amdgcn_mfma_f32_16x16x32_f16(af[ks], bu[ks], au, 0, 0, 0);
      const int h = l15 >> 1, which = l15 & 1;
      float* vw = ws + (which ? OFF_VW2 : OFF_VW1) + ((size_t)(b*Hh + h)*Tt + t)*Nn;
      #pragma unroll
      for (int rg2 = 0; rg2 < 4; ++rg2)
        vw[rowb + rg2] = au[rg2];
    }
  }
}

// ---------------- kernel 3: attn — dense f16 reads, k via readlane, online softmax ----------------
// block = (b,h,half): 256 blocks x 512 thr. Lane owns j; wave ig owns 4 i's.
// k chunk staged linear (lane's slice = conflict-free b128 -> registers);
// per-i k operands via readlane (wave-uniform) feeding v_dot2 SGPR slot.
__global__ __launch_bounds__(512) void k_attn(float* __restrict__ ws) {
  __shared__ uint32_t k_l[TT][256];         // 8 KB: [t][i*8+d2], i local 0..31
  __shared__ uint32_t q_l[TT][8][64];       // 16 KB: [t][d2][j]
  __shared__ float vw1_l[TT][32], vw2_l[TT][32]; // 2 KB
  const int tid = threadIdx.x;
  const int blk = blockIdx.x;         // bh*2 + half
  const int half = blk & 1;
  const int bh = blk >> 1;
  const int b = bh >> 3;
  const int lane = tid & 63;          // j
  const int ig = tid >> 6;            // wave 0..7
  const int j = lane;
  const uint32_t* kh = (const uint32_t*)((const _Float16*)(ws + OFF_KH) + (size_t)bh*Tt*Nn*HD);
  const uint32_t* qh = (const uint32_t*)((const _Float16*)(ws + OFF_QH) + (size_t)bh*Tt*Nn*HD);
  const float* vw1 = ws + OFF_VW1 + (size_t)bh*Tt*Nn;
  const float* vw2 = ws + OFF_VW2 + (size_t)bh*Tt*Nn;
  float* e = ws + OFF_E + (size_t)b*Nn*Nn;
  float m[4], Ssum[4], A1[4], A2[4];
  #pragma unroll
  for (int p = 0; p < 4; ++p) { m[p] = -1e30f; Ssum[p] = 0.f; A1[p] = 0.f; A2[p] = 0.f; }
  const float scale = 0.08838834764831845f; // 1/sqrt(128)

  for (int tc = 0; tc < Tt/TT; ++tc) {
    const int tbase = tc * TT;
    __syncthreads();
    // K-half: 8t x 32i x 8 u32 = 512 uint4; 1 per thread (linear per t)
    {
      int t = tid >> 6, q4 = tid & 63;
      *(uint4*)&k_l[t][q4*4] =
          *(const uint4*)&kh[((size_t)(tbase + t)*Nn)*8 + half*256 + q4*4];
    }
    // Q: 8t x 64j x 8 u32 = 1024 uint4; 2 per thread, transposed to d2-major
    #pragma unroll
    for (int s = 0; s < 2; ++s) {
      int fi = tid + s*512;
      int t = fi >> 7, r = fi & 127;
      int jj = r >> 1, h4 = (r & 1)*4;
      uint4 v = *(const uint4*)&qh[((size_t)(tbase + t)*Nn)*8 + jj*8 + h4];
      q_l[t][h4+0][jj] = v.x;
      q_l[t][h4+1][jj] = v.y;
      q_l[t][h4+2][jj] = v.z;
      q_l[t][h4+3][jj] = v.w;
    }
    // vw: 2 x 8t x 32i = 512; 1 per thread
    {
      int which = tid >> 8, t = (tid >> 5) & 7, il = tid & 31;
      float v = (which ? vw2 : vw1)[(size_t)(tbase + t)*Nn + half*32 + il];
      if (which) vw2_l[t][il] = v; else vw1_l[t][il] = v;
    }
    __syncthreads();

    for (int tt = 0; tt < TT; ++tt) {
      uint32_t qv[8];
      #pragma unroll
      for (int d2 = 0; d2 < 8; ++d2) qv[d2] = q_l[tt][d2][j];
      uint4 ko = *(const uint4*)&k_l[tt][lane*4];  // lane's k slice
      const uint32_t* kop = (const uint32_t*)&ko;
      #pragma unroll
      for (int p = 0; p < 4; ++p) {
        const int iloc = ig*4 + p;
        const int l0 = iloc*2;
        float s = 0.f;
        #pragma unroll
        for (int w = 0; w < 4; ++w) {
          uint32_t klo = bcast_lane(kop[w], l0);
          uint32_t khi = bcast_lane(kop[w], l0 + 1);
          s = fdot2(klo, qv[w], s);
          s = fdot2(khi, qv[4 + w], s);
        }
        s *= scale;
        float mn = fmaxf(m[p], s);
        float cc2 = __expf(m[p] - mn);
        float pp = __expf(s - mn);
        Ssum[p] = fmaf(Ssum[p], cc2, pp);
        A1[p] = fmaf(A1[p], cc2, pp * vw1_l[tt][iloc]);
        A2[p] = fmaf(A2[p], cc2, pp * vw2_l[tt][iloc]);
        m[p] = mn;
      }
    }
  }
  #pragma unroll
  for (int p = 0; p < 4; ++p) {
    const int i = half*32 + ig*4 + p;
    float inv = 1.f / Ssum[p];
    atomicAdd(&e[i*Nn + j], A1[p] * inv);
    atomicAdd(&e[j*Nn + i], A2[p] * inv);
  }
}

// ---------------- kernel 4: decode GRU step + vv ----------------
__global__ __launch_bounds__(384) void k_decode(
    const float* __restrict__ x, const float* __restrict__ W_hh,
    const float* __restrict__ b_hh, const float* __restrict__ W_val,
    const float* __restrict__ b_val, float* __restrict__ ws) {
  __shared__ float h_lds[4][Dd];
  __shared__ float g_lds[4][4*Dd];
  __shared__ float xt[4][Ss];
  const int tid = threadIdx.x;
  const int blk = blockIdx.x;
  const int row0 = blk * 4;
  const int b = row0 >> 6;
  const int n0 = row0 & 63;
  const float* ys = ws + OFF_YS;
  const float* Wx = ws + OFF_WX;
  const float* bxp = ws + OFF_BX;
  if (tid < Dd) {
    for (int r = 0; r < 4; ++r)
      h_lds[r][tid] = ys[(size_t)((Tt-1)*BN + row0 + r)*Dd + tid];
  }
  if (tid >= 320 && tid < 336) {
    int q = tid - 320; int r = q >> 2, s = q & 3;
    xt[r][s] = x[((size_t)(b*(Tt+1) + Tt)*Nn + (n0 + r))*Ss + s];
  }
  const int c = tid;
  const float bhh = b_hh[c];
  const float wx0 = Wx[0*G3 + c], wx1 = Wx[1*G3 + c], wx2 = Wx[2*G3 + c], wx3 = Wx[3*G3 + c];
  const float bxv = bxp[c];
  __syncthreads();
  float acc[4] = {bhh, bhh, bhh, bhh};
  for (int k = 0; k < Dd; k += 4) {
    float w0 = W_hh[(k+0)*G3 + c];
    float w1 = W_hh[(k+1)*G3 + c];
    float w2 = W_hh[(k+2)*G3 + c];
    float w3 = W_hh[(k+3)*G3 + c];
    #pragma unroll
    for (int r = 0; r < 4; ++r) {
      float4 hv = *(const float4*)&h_lds[r][k];
      acc[r] = fmaf(hv.x, w0, acc[r]);
      acc[r] = fmaf(hv.y, w1, acc[r]);
      acc[r] = fmaf(hv.z, w2, acc[r]);
      acc[r] = fmaf(hv.w, w3, acc[r]);
    }
  }
  float gi[4];
  #pragma unroll
  for (int r = 0; r < 4; ++r) {
    float g = bxv;
    g = fmaf(xt[r][0], wx0, g);
    g = fmaf(xt[r][1], wx1, g);
    g = fmaf(xt[r][2], wx2, g);
    g = fmaf(xt[r][3], wx3, g);
    gi[r] = g;
  }
  if (c < 2*Dd) {
    #pragma unroll
    for (int r = 0; r < 4; ++r) g_lds[r][c] = acc[r] + gi[r];
  } else {
    #pragma unroll
    for (int r = 0; r < 4; ++r) { g_lds[r][c] = gi[r]; g_lds[r][c + Dd] = acc[r]; }
  }
  __syncthreads();
  if (tid < Dd) {
    const int d = tid;
    #pragma unroll
    for (int r = 0; r < 4; ++r) {
      float rg = fast_sigmoid(g_lds[r][d]);
      float zg = fast_sigmoid(g_lds[r][Dd + d]);
      float ng = fast_tanh(fmaf(rg, g_lds[r][3*Dd + d], g_lds[r][2*Dd + d]));
      float hn = fmaf(zg, h_lds[r][d] - ng, ng);
      h_lds[r][d] = hn;
    }
  }
  __syncthreads();
  if (tid < Dd) {
    const int c2 = tid;
    for (int r = 0; r < 4; ++r) {
      float a = b_val[c2];
      for (int k = 0; k < Dd; k += 4) {
        float4 hv = *(const float4*)&h_lds[r][k];
        a = fmaf(hv.x, W_val[(k+0)*Dd + c2], a);
        a = fmaf(hv.y, W_val[(k+1)*Dd + c2], a);
        a = fmaf(hv.z, W_val[(k+2)*Dd + c2], a);
        a = fmaf(hv.w, W_val[(k+3)*Dd + c2], a);
      }
      ws[OFF_VV + (size_t)(row0 + r)*Dd + c2] = a;
    }
  }
}

// ---------------- kernel 5: weight/p/dec/mu/sig ----------------
__global__ __launch_bounds__(256) void k_final(
    const float* __restrict__ W_dec, const float* __restrict__ b_dec,
    const float* __restrict__ W_mu, const float* __restrict__ b_mu,
    const float* __restrict__ W_sig, const float* __restrict__ b_sig,
    const float* __restrict__ b_att, float* __restrict__ ws,
    float* __restrict__ out) {
  __shared__ float vvl[64][Dd];
  __shared__ float wl[16][64];
  __shared__ float pl[16][Dd];
  __shared__ float ddl[16][Dd];
  const int tid = threadIdx.x;
  const int blk = blockIdx.x;
  const int b = blk >> 2, iq = blk & 3, i0 = iq*16;
  const float* vv = ws + OFF_VV + (size_t)b*64*Dd;
  const float* e = ws + OFF_E + (size_t)b*Nn*Nn;
  const float batt = b_att[0];
  for (int idx = tid; idx < 64*Dd; idx += 256) ((float*)vvl)[idx] = vv[idx];
  for (int idx = tid; idx < 16*64; idx += 256) {
    int il = idx >> 6, jj = idx & 63;
    int i = i0 + il;
    wl[il][jj] = (i == jj) ? 0.f : fast_tanh(e[i*Nn + jj] + batt + 0.5f);
  }
  __syncthreads();
  {
    const int d = tid & 127, ih = tid >> 7;
    #pragma unroll
    for (int kk2 = 0; kk2 < 8; ++kk2) {
      int il = ih*8 + kk2;
      float a = 0.f;
      for (int jj = 0; jj < 64; ++jj) a = fmaf(wl[il][jj], vvl[jj][d], a);
      pl[il][d] = a * (1.f/64.f);
    }
  }
  __syncthreads();
  {
    const int e2 = tid & 127, ih = tid >> 7;
    #pragma unroll
    for (int kk2 = 0; kk2 < 8; ++kk2) {
      int il = ih*8 + kk2;
      float a = b_dec[e2];
      for (int c2 = 0; c2 < Dd; ++c2) a = fmaf(vvl[i0 + il][c2], W_dec[c2*Dd + e2], a);
      for (int c2 = 0; c2 < Dd; ++c2) a = fmaf(pl[il][c2], W_dec[(Dd + c2)*Dd + e2], a);
      ddl[il][e2] = a;
    }
  }
  __syncthreads();
  if (tid < 128) {
    const int il = tid >> 3, g = tid & 7, which = g >> 2, s = g & 3;
    const float* W = which ? W_sig : W_mu;
    float a = which ? b_sig[s] : b_mu[s];
    for (int k = 0; k < Dd; ++k) a = fmaf(ddl[il][k], W[k*Ss + s], a);
    if (which) a = 1.f/(1.f + __expf(-a)) + 1e-6f;
    out[(size_t)which*(Bb*Nn*Ss) + (size_t)(b*64 + i0 + il)*Ss + s] = a;
  }
}

extern "C" void kernel_launch(void* const* d_in, const int* in_sizes, int n_in,
                              void* d_out, int out_size, void* d_ws, size_t ws_size,
                              hipStream_t stream) {
  const float* x     = (const float*)d_in[0];
  const float* W_se  = (const float*)d_in[1];
  const float* b_se  = (const float*)d_in[2];
  const float* W_init= (const float*)d_in[3];
  const float* b_init= (const float*)d_in[4];
  const float* W_ih  = (const float*)d_in[5];
  const float* W_hh  = (const float*)d_in[6];
  const float* b_ih  = (const float*)d_in[7];
  const float* b_hh  = (const float*)d_in[8];
  const float* W_kc  = (const float*)d_in[9];
  const float* W_qc  = (const float*)d_in[10];
  const float* W_vc  = (const float*)d_in[11];
  const float* W_att = (const float*)d_in[12];
  const float* b_att = (const float*)d_in[13];
  const float* W_val = (const float*)d_in[14];
  const float* b_val = (const float*)d_in[15];
  const float* W_dec = (const float*)d_in[16];
  const float* b_dec = (const float*)d_in[17];
  const float* W_mu  = (const float*)d_in[18];
  const float* b_mu  = (const float*)d_in[19];
  const float* W_sig = (const float*)d_in[20];
  const float* b_sig = (const float*)d_in[21];
  float* ws = (float*)d_ws;
  float* out = (float*)d_out;

  if (ws_size < (size_t)WS_FLOATS * sizeof(float)) return;

  hipMemsetAsync(ws + OFF_E, 0, (size_t)Bb*Nn*Nn*sizeof(float), stream);
  k_precompute<<<42, 384, 0, stream>>>(W_se, b_se, W_ih, b_ih, W_hh, W_kc, W_qc, W_vc, W_att, ws);
  k_gru<<<BN/4, 512, 0, stream>>>(x, W_init, b_init, b_hh, ws);
  k_kqv<<<Bb*Tt, 256, 0, stream>>>(ws);
  k_attn<<<Bb*Hh*2, 512, 0, stream>>>(ws);
  k_decode<<<BN/4, 384, 0, stream>>>(x, W_hh, b_hh, W_val, b_val, ws);
  k_final<<<Bb*4, 256, 0, stream>>>(W_dec, b_dec, W_mu, b_mu, W_sig, b_sig, b_att, ws, out);
}

// Round 13
// 212.265 us; speedup vs baseline: 1.0523x; 1.0523x over previous
//
#include <hip/hip_runtime.h>
#include <math.h>

#define Bb 16
#define Tt 64
#define Nn 64
#define Ss 4
#define Dd 128
#define Hh 8
#define HD 16
#define BN 1024
#define G3 384   // 3*D
#define TT 8     // t-chunk for k_attn

// workspace layout (in floats)
#define OFF_WX   0                              // 4*384
#define OFF_BX   1536                           // 384
#define OFF_YS   4096                           // T*BN*D
#define OFF_KH   (OFF_YS + Tt*BN*Dd)            // f16 [b,h][t][n][16]
#define OFF_QH   (OFF_KH + Bb*Hh*Tt*Nn*HD/2)
#define OFF_VW1  (OFF_QH + Bb*Hh*Tt*Nn*HD/2)    // f32 [b,h][t][n]
#define OFF_VW2  (OFF_VW1 + Bb*Hh*Tt*Nn)
#define OFF_E    (OFF_VW2 + Bb*Hh*Tt*Nn)        // B*N*N
#define OFF_VV   (OFF_E + Bb*Nn*Nn)             // BN*D
#define OFF_WKQ  (OFF_VV + BN*Dd)               // f16 frag [W_kc|W_qc|u]: 17408 floats
#define OFF_WT   (OFF_WKQ + 17408)              // f16 frag W_hh: 24576 floats
#define WS_FLOATS (OFF_WT + 24576)

typedef _Float16 half2_t __attribute__((ext_vector_type(2)));
typedef _Float16 f16x8 __attribute__((ext_vector_type(8)));
typedef float f32x4 __attribute__((ext_vector_type(4)));

__device__ __forceinline__ float fast_sigmoid(float v) {
  return 1.f / (1.f + __expf(-v));
}
__device__ __forceinline__ float fast_tanh(float v) {
  float e2 = __expf(2.f * v);
  return 1.f - 2.f / (e2 + 1.f);
}
__device__ __forceinline__ float fdot2(uint32_t a, uint32_t b, float c) {
  half2_t av = __builtin_bit_cast(half2_t, a);
  half2_t bv = __builtin_bit_cast(half2_t, b);
#if __has_builtin(__builtin_amdgcn_fdot2)
  return __builtin_amdgcn_fdot2(av, bv, c, false);
#else
  return c + (float)av.x * (float)bv.x + (float)av.y * (float)bv.y;
#endif
}
__device__ __forceinline__ uint32_t bcast_lane(uint32_t v, int l) {
  return (uint32_t)__builtin_amdgcn_readlane((int)v, l);
}

// ---------------- kernel 0: fold weights + pack W_hh / W_kq / u fragments ----------------
__global__ __launch_bounds__(384) void k_precompute(
    const float* __restrict__ W_se, const float* __restrict__ b_se,
    const float* __restrict__ W_ih, const float* __restrict__ b_ih,
    const float* __restrict__ W_hh,
    const float* __restrict__ W_kc, const float* __restrict__ W_qc,
    const float* __restrict__ W_vc, const float* __restrict__ W_att,
    float* __restrict__ ws) {
  const int tid = threadIdx.x;
  if (blockIdx.x >= 25) {
    const int nt = blockIdx.x - 25;  // 0..16
    _Float16* WF = (_Float16*)(ws + OFF_WKQ);
    for (int idx = tid; idx < 4*64*8; idx += 384) {
      int ks = idx >> 9, l = (idx >> 3) & 63, j = idx & 7;
      int k = ks*32 + (l >> 4)*8 + j;
      int c16 = l & 15;
      float v;
      if (nt < 16) {
        int cg = nt*16 + c16;
        v = (cg < Dd) ? W_kc[(size_t)k*Dd + cg] : W_qc[(size_t)k*Dd + cg - Dd];
      } else {
        int h = c16 >> 1, which = c16 & 1;
        float s = 0.f;
        for (int d = 0; d < HD; ++d)
          s = fmaf(W_vc[(size_t)k*Dd + h*HD + d], W_att[which*Dd + h*HD + d], s);
        v = s;
      }
      WF[(size_t)((nt*4 + ks)*64 + l)*8 + j] = (_Float16)v;
    }
    return;
  }
  if (blockIdx.x > 0) {
    const int nt = blockIdx.x - 1;  // 0..23
    _Float16* WF = (_Float16*)(ws + OFF_WT);
    for (int idx = tid; idx < 4*64*8; idx += 384) {
      int ks = idx >> 9, l = (idx >> 3) & 63, j = idx & 7;
      int k = ks*32 + (l >> 4)*8 + j;
      int c = nt*16 + (l & 15);
      WF[(size_t)((nt*4 + ks)*64 + l)*8 + j] = (_Float16)W_hh[(size_t)k*G3 + c];
    }
    return;
  }
  const int c = tid;
  float* Wx = ws + OFF_WX; float* bx = ws + OFF_BX;
  float accb = b_ih[c];
  float a0 = 0.f, a1 = 0.f, a2 = 0.f, a3 = 0.f;
  for (int k = 0; k < Dd; ++k) {
    float w = W_ih[k*G3 + c];
    accb = fmaf(b_se[k], w, accb);
    a0 = fmaf(W_se[0*Dd + k], w, a0);
    a1 = fmaf(W_se[1*Dd + k], w, a1);
    a2 = fmaf(W_se[2*Dd + k], w, a2);
    a3 = fmaf(W_se[3*Dd + k], w, a3);
  }
  bx[c] = accb;
  Wx[0*G3 + c] = a0; Wx[1*G3 + c] = a1; Wx[2*G3 + c] = a2; Wx[3*G3 + c] = a3;
}

// ---------------- kernel 1: GRU via MFMA (f16), W fragments register-resident ----------------
__global__ __launch_bounds__(512, 2) void k_gru(
    const float* __restrict__ x, const float* __restrict__ W_init,
    const float* __restrict__ b_init,
    const float* __restrict__ b_hh, float* __restrict__ ws) {
  __shared__ __align__(16) _Float16 h_l[4][Dd + 8];
  __shared__ float gg[4][G3];
  __shared__ float xt_l[Tt+1][4][Ss];
  const int tid = threadIdx.x;
  const int wave = tid >> 6;
  const int lane = tid & 63;
  const int l15 = lane & 15;
  const int lk = lane >> 4;
  const int blk = blockIdx.x;
  const int row0 = blk * 4;
  const int b = row0 >> 6;
  const int n0 = row0 & 63;
  float* ys = ws + OFF_YS;
  const float* Wx = ws + OFF_WX;
  const float* bxp = ws + OFF_BX;

  const f16x8* WF = (const f16x8*)(ws + OFF_WT);
  f16x8 wf[3][4];
  #pragma unroll
  for (int i = 0; i < 3; ++i)
    #pragma unroll
    for (int ks = 0; ks < 4; ++ks)
      wf[i][ks] = WF[(size_t)((wave*3 + i)*4 + ks)*64 + lane];
  float br[3];
  #pragma unroll
  for (int i = 0; i < 3; ++i) br[i] = b_hh[(wave*3 + i)*16 + l15];

  const int row = tid >> 7, d = tid & 127;
  float wxr[3][4], bx3[3];
  #pragma unroll
  for (int g = 0; g < 3; ++g) {
    bx3[g] = bxp[g*Dd + d];
    #pragma unroll
    for (int s = 0; s < 4; ++s) wxr[g][s] = Wx[s*G3 + g*Dd + d];
  }

  for (int idx = tid; idx < (Tt+1)*4*Ss; idx += 512) {
    int t = idx >> 4, r = (idx >> 2) & 3, s = idx & 3;
    xt_l[t][r][s] = x[((size_t)(b*(Tt+1) + t)*Nn + (n0 + r))*Ss + s];
  }
  __syncthreads();

  float hprev;
  {
    float h0 = b_init[d];
    #pragma unroll
    for (int s = 0; s < Ss; ++s)
      h0 = fmaf(xt_l[0][row][s], W_init[s*Dd + d], h0);
    hprev = h0;
    h_l[row][d] = (_Float16)h0;
  }
  __syncthreads();

  for (int t = 0; t < Tt; ++t) {
    f16x8 af[4];
    #pragma unroll
    for (int ks = 0; ks < 4; ++ks)
      af[ks] = *(const f16x8*)&h_l[l15 & 3][ks*32 + lk*8];
    #pragma unroll
    for (int i = 0; i < 3; ++i) {
      f32x4 acc = {br[i], br[i], br[i], br[i]};
      #pragma unroll
      for (int ks = 0; ks < 4; ++ks)
        acc = __builtin_amdgcn_mfma_f32_16x16x32_f16(af[ks], wf[i][ks], acc, 0, 0, 0);
      if (lane < 16) {
        const int col = (wave*3 + i)*16 + l15;
        gg[0][col] = acc[0];
        gg[1][col] = acc[1];
        gg[2][col] = acc[2];
        gg[3][col] = acc[3];
      }
    }
    __syncthreads();
    {
      float gi_r = bx3[0], gi_z = bx3[1], gi_n = bx3[2];
      #pragma unroll
      for (int s = 0; s < 4; ++s) {
        float xv = xt_l[t][row][s];
        gi_r = fmaf(xv, wxr[0][s], gi_r);
        gi_z = fmaf(xv, wxr[1][s], gi_z);
        gi_n = fmaf(xv, wxr[2][s], gi_n);
      }
      float rg = fast_sigmoid(gi_r + gg[row][d]);
      float zg = fast_sigmoid(gi_z + gg[row][Dd + d]);
      float ng = fast_tanh(fmaf(rg, gg[row][2*Dd + d], gi_n));
      float hnew = fmaf(zg, hprev - ng, ng);
      hprev = hnew;
      h_l[row][d] = (_Float16)hnew;
      ys[(size_t)(t*BN + row0 + row)*Dd + d] = hnew;
    }
    __syncthreads();
  }
}

// ---------------- kernel 2: k,q,vw via MFMA (f16); K/Q written f16 head-major ----------------
__global__ __launch_bounds__(256, 2) void k_kqv(float* __restrict__ ws) {
  __shared__ __align__(16) _Float16 ysl[64][136];
  const int tid = threadIdx.x;
  const int blk = blockIdx.x;    // b*T + t
  const int b = blk >> 6, t = blk & 63;
  const int wave = tid >> 6, lane = tid & 63;
  const int l15 = lane & 15, lk = lane >> 4;

  const f16x8* WKQ = (const f16x8*)(ws + OFF_WKQ);
  f16x8 bf0[4], bf1[4], bf2[4], bf3[4], bu[4];
  #pragma unroll
  for (int ks = 0; ks < 4; ++ks) {
    bf0[ks] = WKQ[(size_t)((wave*4 + 0)*4 + ks)*64 + lane];
    bf1[ks] = WKQ[(size_t)((wave*4 + 1)*4 + ks)*64 + lane];
    bf2[ks] = WKQ[(size_t)((wave*4 + 2)*4 + ks)*64 + lane];
    bf3[ks] = WKQ[(size_t)((wave*4 + 3)*4 + ks)*64 + lane];
    bu[ks]  = WKQ[(size_t)(16*4 + ks)*64 + lane];
  }

  const float* ysrc = ws + OFF_YS + ((size_t)t*BN + b*64)*Dd;
  for (int idx = tid; idx < 64*16; idx += 256) {
    int r = idx >> 4, k8 = (idx & 15) * 8;
    float4 v0 = *(const float4*)&ysrc[r*Dd + k8];
    float4 v1 = *(const float4*)&ysrc[r*Dd + k8 + 4];
    f16x8 hv;
    hv[0] = (_Float16)v0.x; hv[1] = (_Float16)v0.y;
    hv[2] = (_Float16)v0.z; hv[3] = (_Float16)v0.w;
    hv[4] = (_Float16)v1.x; hv[5] = (_Float16)v1.y;
    hv[6] = (_Float16)v1.z; hv[7] = (_Float16)v1.w;
    *(f16x8*)&ysl[r][k8] = hv;
  }
  __syncthreads();

  _Float16* khd = (_Float16*)(ws + OFF_KH);
  _Float16* qhd = (_Float16*)(ws + OFF_QH);

  #pragma unroll
  for (int mt = 0; mt < 4; ++mt) {
    f16x8 af[4];
    #pragma unroll
    for (int ks = 0; ks < 4; ++ks)
      af[ks] = *(const f16x8*)&ysl[mt*16 + l15][ks*32 + lk*8];
    f32x4 a0 = {0.f,0.f,0.f,0.f}, a1 = a0, a2 = a0, a3 = a0;
    #pragma unroll
    for (int ks = 0; ks < 4; ++ks) {
      a0 = __builtin_amdgcn_mfma_f32_16x16x32_f16(af[ks], bf0[ks], a0, 0, 0, 0);
      a1 = __builtin_amdgcn_mfma_f32_16x16x32_f16(af[ks], bf1[ks], a1, 0, 0, 0);
      a2 = __builtin_amdgcn_mfma_f32_16x16x32_f16(af[ks], bf2[ks], a2, 0, 0, 0);
      a3 = __builtin_amdgcn_mfma_f32_16x16x32_f16(af[ks], bf3[ks], a3, 0, 0, 0);
    }
    const int rowb = mt*16 + lk*4;
    #pragma unroll
    for (int nti = 0; nti < 4; ++nti) {
      f32x4 av = (nti == 0) ? a0 : (nti == 1) ? a1 : (nti == 2) ? a2 : a3;
      const int gc = wave*64 + nti*16 + l15;
      const int hh = (gc >> 4) & 7;
      const int dd2 = gc & 15;
      _Float16* base = (gc < Dd) ? khd : qhd;
      const size_t rowbase = ((size_t)(b*Hh + hh)*Tt + t)*Nn*HD;
      #pragma unroll
      for (int rg2 = 0; rg2 < 4; ++rg2)
        base[rowbase + (size_t)(rowb + rg2)*HD + dd2] = (_Float16)av[rg2];
    }
    if (wave == 3) {
      f32x4 au = {0.f,0.f,0.f,0.f};
      #pragma unroll
      for (int ks = 0; ks < 4; ++ks)
        au = __builtin_amdgcn_mfma_f32_16x16x32_f16(af[ks], bu[ks], au, 0, 0, 0);
      const int h = l15 >> 1, which = l15 & 1;
      float* vw = ws + (which ? OFF_VW2 : OFF_VW1) + ((size_t)(b*Hh + h)*Tt + t)*Nn;
      #pragma unroll
      for (int rg2 = 0; rg2 < 4; ++rg2)
        vw[rowb + rg2] = au[rg2];
    }
  }
}

// ---------------- kernel 3: attn — clamp-exp softmax (no max tracking), 2 blocks/CU ----------------
// block = (b,h,quarter): 512 blocks x 512 thr (16 waves/CU). Lane owns j; wave
// ig owns 2 i's. Scores tiny by construction (sigma~0.4); clamp(+-60) makes
// exp overflow/underflow impossible. k via lane-slice + readlane; LDS b64 reads.
__global__ __launch_bounds__(512) void k_attn(float* __restrict__ ws) {
  __shared__ __align__(16) uint32_t k_l[TT][16][8];   // 4 KB
  __shared__ __align__(8) uint2 q_l2[TT][4][64];      // 16 KB (q pairs d2-major)
  __shared__ float vw1_l[TT][16], vw2_l[TT][16];      // 1 KB
  const int tid = threadIdx.x;
  const int blk = blockIdx.x;         // bh*4 + quarter
  const int quarter = blk & 3;
  const int bh = blk >> 2;
  const int b = bh >> 3;
  const int i0 = quarter * 16;
  const int lane = tid & 63;          // j
  const int ig = tid >> 6;            // wave 0..7 -> i pair
  const int j = lane;
  const uint32_t* kh = (const uint32_t*)((const _Float16*)(ws + OFF_KH) + (size_t)bh*Tt*Nn*HD);
  const uint32_t* qh = (const uint32_t*)((const _Float16*)(ws + OFF_QH) + (size_t)bh*Tt*Nn*HD);
  const float* vw1 = ws + OFF_VW1 + (size_t)bh*Tt*Nn;
  const float* vw2 = ws + OFF_VW2 + (size_t)bh*Tt*Nn;
  float* e = ws + OFF_E + (size_t)b*Nn*Nn;
  float S0 = 0.f, S1 = 0.f, A10 = 0.f, A11 = 0.f, A20 = 0.f, A21 = 0.f;
  const float scale = 0.08838834764831845f; // 1/sqrt(128)

  for (int tc = 0; tc < Tt/TT; ++tc) {
    const int tbase = tc * TT;
    __syncthreads();
    // K quarter: 8t x 16i x 8u32 = 256 uint4; tid<256 one each
    if (tid < 256) {
      int t = tid >> 5, il = (tid >> 1) & 15, d4 = tid & 1;
      *(uint4*)&k_l[t][il][d4*4] =
          *(const uint4*)&kh[((size_t)(tbase + t)*Nn + i0 + il)*8 + d4*4];
    }
    // Q: 8t x 64j x 8u32 = 1024 uint4; 2 per thread, to d2-pair-major
    #pragma unroll
    for (int s = 0; s < 2; ++s) {
      int fi = tid + s*512;
      int t = fi >> 7, r = fi & 127;
      int jj = r >> 1, h4 = (r & 1)*4;
      uint4 v = *(const uint4*)&qh[((size_t)(tbase + t)*Nn + jj)*8 + h4];
      q_l2[t][(h4 >> 1) + 0][jj] = make_uint2(v.x, v.y);
      q_l2[t][(h4 >> 1) + 1][jj] = make_uint2(v.z, v.w);
    }
    // vw: 2 x 8t x 16i = 256; tid<256 one each
    if (tid < 256) {
      int which = tid >> 7, t = (tid >> 4) & 7, il = tid & 15;
      float v = (which ? vw2 : vw1)[(size_t)(tbase + t)*Nn + i0 + il];
      if (which) vw2_l[t][il] = v; else vw1_l[t][il] = v;
    }
    __syncthreads();

    for (int tt = 0; tt < TT; ++tt) {
      uint2 kp = ((const uint2*)&k_l[tt][0][0])[lane];  // lane's flat k slice
      uint2 q0 = q_l2[tt][0][j];
      uint2 q1 = q_l2[tt][1][j];
      uint2 q2 = q_l2[tt][2][j];
      uint2 q3 = q_l2[tt][3][j];
      float2 v1 = *(const float2*)&vw1_l[tt][ig*2];
      float2 v2 = *(const float2*)&vw2_l[tt][ig*2];
      #pragma unroll
      for (int p = 0; p < 2; ++p) {
        const int base = (ig*2 + p)*4;
        float s = 0.f;
        s = fdot2(bcast_lane(kp.x, base+0), q0.x, s);
        s = fdot2(bcast_lane(kp.y, base+0), q0.y, s);
        s = fdot2(bcast_lane(kp.x, base+1), q1.x, s);
        s = fdot2(bcast_lane(kp.y, base+1), q1.y, s);
        s = fdot2(bcast_lane(kp.x, base+2), q2.x, s);
        s = fdot2(bcast_lane(kp.y, base+2), q2.y, s);
        s = fdot2(bcast_lane(kp.x, base+3), q3.x, s);
        s = fdot2(bcast_lane(kp.y, base+3), q3.y, s);
        s = fminf(fmaxf(s * scale, -60.f), 60.f);
        float ee = __expf(s);
        if (p == 0) {
          S0 += ee; A10 = fmaf(ee, v1.x, A10); A20 = fmaf(ee, v2.x, A20);
        } else {
          S1 += ee; A11 = fmaf(ee, v1.y, A11); A21 = fmaf(ee, v2.y, A21);
        }
      }
    }
  }
  {
    const int i = i0 + ig*2;
    float inv0 = 1.f / S0, inv1 = 1.f / S1;
    atomicAdd(&e[i*Nn + j], A10 * inv0);
    atomicAdd(&e[j*Nn + i], A20 * inv0);
    atomicAdd(&e[(i+1)*Nn + j], A11 * inv1);
    atomicAdd(&e[j*Nn + i + 1], A21 * inv1);
  }
}

// ---------------- kernel 4: decode GRU step + vv ----------------
__global__ __launch_bounds__(384) void k_decode(
    const float* __restrict__ x, const float* __restrict__ W_hh,
    const float* __restrict__ b_hh, const float* __restrict__ W_val,
    const float* __restrict__ b_val, float* __restrict__ ws) {
  __shared__ float h_lds[4][Dd];
  __shared__ float g_lds[4][4*Dd];
  __shared__ float xt[4][Ss];
  const int tid = threadIdx.x;
  const int blk = blockIdx.x;
  const int row0 = blk * 4;
  const int b = row0 >> 6;
  const int n0 = row0 & 63;
  const float* ys = ws + OFF_YS;
  const float* Wx = ws + OFF_WX;
  const float* bxp = ws + OFF_BX;
  if (tid < Dd) {
    for (int r = 0; r < 4; ++r)
      h_lds[r][tid] = ys[(size_t)((Tt-1)*BN + row0 + r)*Dd + tid];
  }
  if (tid >= 320 && tid < 336) {
    int q = tid - 320; int r = q >> 2, s = q & 3;
    xt[r][s] = x[((size_t)(b*(Tt+1) + Tt)*Nn + (n0 + r))*Ss + s];
  }
  const int c = tid;
  const float bhh = b_hh[c];
  const float wx0 = Wx[0*G3 + c], wx1 = Wx[1*G3 + c], wx2 = Wx[2*G3 + c], wx3 = Wx[3*G3 + c];
  const float bxv = bxp[c];
  __syncthreads();
  float acc[4] = {bhh, bhh, bhh, bhh};
  for (int k = 0; k < Dd; k += 4) {
    float w0 = W_hh[(k+0)*G3 + c];
    float w1 = W_hh[(k+1)*G3 + c];
    float w2 = W_hh[(k+2)*G3 + c];
    float w3 = W_hh[(k+3)*G3 + c];
    #pragma unroll
    for (int r = 0; r < 4; ++r) {
      float4 hv = *(const float4*)&h_lds[r][k];
      acc[r] = fmaf(hv.x, w0, acc[r]);
      acc[r] = fmaf(hv.y, w1, acc[r]);
      acc[r] = fmaf(hv.z, w2, acc[r]);
      acc[r] = fmaf(hv.w, w3, acc[r]);
    }
  }
  float gi[4];
  #pragma unroll
  for (int r = 0; r < 4; ++r) {
    float g = bxv;
    g = fmaf(xt[r][0], wx0, g);
    g = fmaf(xt[r][1], wx1, g);
    g = fmaf(xt[r][2], wx2, g);
    g = fmaf(xt[r][3], wx3, g);
    gi[r] = g;
  }
  if (c < 2*Dd) {
    #pragma unroll
    for (int r = 0; r < 4; ++r) g_lds[r][c] = acc[r] + gi[r];
  } else {
    #pragma unroll
    for (int r = 0; r < 4; ++r) { g_lds[r][c] = gi[r]; g_lds[r][c + Dd] = acc[r]; }
  }
  __syncthreads();
  if (tid < Dd) {
    const int d = tid;
    #pragma unroll
    for (int r = 0; r < 4; ++r) {
      float rg = fast_sigmoid(g_lds[r][d]);
      float zg = fast_sigmoid(g_lds[r][Dd + d]);
      float ng = fast_tanh(fmaf(rg, g_lds[r][3*Dd + d], g_lds[r][2*Dd + d]));
      float hn = fmaf(zg, h_lds[r][d] - ng, ng);
      h_lds[r][d] = hn;
    }
  }
  __syncthreads();
  if (tid < Dd) {
    const int c2 = tid;
    for (int r = 0; r < 4; ++r) {
      float a = b_val[c2];
      for (int k = 0; k < Dd; k += 4) {
        float4 hv = *(const float4*)&h_lds[r][k];
        a = fmaf(hv.x, W_val[(k+0)*Dd + c2], a);
        a = fmaf(hv.y, W_val[(k+1)*Dd + c2], a);
        a = fmaf(hv.z, W_val[(k+2)*Dd + c2], a);
        a = fmaf(hv.w, W_val[(k+3)*Dd + c2], a);
      }
      ws[OFF_VV + (size_t)(row0 + r)*Dd + c2] = a;
    }
  }
}

// ---------------- kernel 5: weight/p/dec/mu/sig ----------------
__global__ __launch_bounds__(256) void k_final(
    const float* __restrict__ W_dec, const float* __restrict__ b_dec,
    const float* __restrict__ W_mu, const float* __restrict__ b_mu,
    const float* __restrict__ W_sig, const float* __restrict__ b_sig,
    const float* __restrict__ b_att, float* __restrict__ ws,
    float* __restrict__ out) {
  __shared__ float vvl[64][Dd];
  __shared__ float wl[16][64];
  __shared__ float pl[16][Dd];
  __shared__ float ddl[16][Dd];
  const int tid = threadIdx.x;
  const int blk = blockIdx.x;
  const int b = blk >> 2, iq = blk & 3, i0 = iq*16;
  const float* vv = ws + OFF_VV + (size_t)b*64*Dd;
  const float* e = ws + OFF_E + (size_t)b*Nn*Nn;
  const float batt = b_att[0];
  for (int idx = tid; idx < 64*Dd; idx += 256) ((float*)vvl)[idx] = vv[idx];
  for (int idx = tid; idx < 16*64; idx += 256) {
    int il = idx >> 6, jj = idx & 63;
    int i = i0 + il;
    wl[il][jj] = (i == jj) ? 0.f : fast_tanh(e[i*Nn + jj] + batt + 0.5f);
  }
  __syncthreads();
  {
    const int d = tid & 127, ih = tid >> 7;
    #pragma unroll
    for (int kk2 = 0; kk2 < 8; ++kk2) {
      int il = ih*8 + kk2;
      float a = 0.f;
      for (int jj = 0; jj < 64; ++jj) a = fmaf(wl[il][jj], vvl[jj][d], a);
      pl[il][d] = a * (1.f/64.f);
    }
  }
  __syncthreads();
  {
    const int e2 = tid & 127, ih = tid >> 7;
    #pragma unroll
    for (int kk2 = 0; kk2 < 8; ++kk2) {
      int il = ih*8 + kk2;
      float a = b_dec[e2];
      for (int c2 = 0; c2 < Dd; ++c2) a = fmaf(vvl[i0 + il][c2], W_dec[c2*Dd + e2], a);
      for (int c2 = 0; c2 < Dd; ++c2) a = fmaf(pl[il][c2], W_dec[(Dd + c2)*Dd + e2], a);
      ddl[il][e2] = a;
    }
  }
  __syncthreads();
  if (tid < 128) {
    const int il = tid >> 3, g = tid & 7, which = g >> 2, s = g & 3;
    const float* W = which ? W_sig : W_mu;
    float a = which ? b_sig[s] : b_mu[s];
    for (int k = 0; k < Dd; ++k) a = fmaf(ddl[il][k], W[k*Ss + s], a);
    if (which) a = 1.f/(1.f + __expf(-a)) + 1e-6f;
    out[(size_t)which*(Bb*Nn*Ss) + (size_t)(b*64 + i0 + il)*Ss + s] = a;
  }
}

extern "C" void kernel_launch(void* const* d_in, const int* in_sizes, int n_in,
                              void* d_out, int out_size, void* d_ws, size_t ws_size,
                              hipStream_t stream) {
  const float* x     = (const float*)d_in[0];
  const float* W_se  = (const float*)d_in[1];
  const float* b_se  = (const float*)d_in[2];
  const float* W_init= (const float*)d_in[3];
  const float* b_init= (const float*)d_in[4];
  const float* W_ih  = (const float*)d_in[5];
  const float* W_hh  = (const float*)d_in[6];
  const float* b_ih  = (const float*)d_in[7];
  const float* b_hh  = (const float*)d_in[8];
  const float* W_kc  = (const float*)d_in[9];
  const float* W_qc  = (const float*)d_in[10];
  const float* W_vc  = (const float*)d_in[11];
  const float* W_att = (const float*)d_in[12];
  const float* b_att = (const float*)d_in[13];
  const float* W_val = (const float*)d_in[14];
  const float* b_val = (const float*)d_in[15];
  const float* W_dec = (const float*)d_in[16];
  const float* b_dec = (const float*)d_in[17];
  const float* W_mu  = (const float*)d_in[18];
  const float* b_mu  = (const float*)d_in[19];
  const float* W_sig = (const float*)d_in[20];
  const float* b_sig = (const float*)d_in[21];
  float* ws = (float*)d_ws;
  float* out = (float*)d_out;

  if (ws_size < (size_t)WS_FLOATS * sizeof(float)) return;

  hipMemsetAsync(ws + OFF_E, 0, (size_t)Bb*Nn*Nn*sizeof(float), stream);
  k_precompute<<<42, 384, 0, stream>>>(W_se, b_se, W_ih, b_ih, W_hh, W_kc, W_qc, W_vc, W_att, ws);
  k_gru<<<BN/4, 512, 0, stream>>>(x, W_init, b_init, b_hh, ws);
  k_kqv<<<Bb*Tt, 256, 0, stream>>>(ws);
  k_attn<<<Bb*Hh*4, 512, 0, stream>>>(ws);
  k_decode<<<BN/4, 384, 0, stream>>>(x, W_hh, b_hh, W_val, b_val, ws);
  k_final<<<Bb*4, 256, 0, stream>>>(W_dec, b_dec, W_mu, b_mu, W_sig, b_sig, b_att, ws, out);
}

// Round 14
// 169.863 us; speedup vs baseline: 1.3150x; 1.2496x over previous
//
#include <hip/hip_runtime.h>
#include <math.h>

#define Bb 16
#define Tt 64
#define Nn 64
#define Ss 4
#define Dd 128
#define Hh 8
#define HD 16
#define BN 1024
#define G3 384   // 3*D
#define TT 8     // t-chunk for k_attn

// workspace layout (in floats)
#define OFF_WX   0                              // 4*384
#define OFF_BX   1536                           // 384
#define OFF_YS   4096                           // T*BN*D
#define OFF_KH   (OFF_YS + Tt*BN*Dd)            // f16 [b,h][t][n][16]
#define OFF_QH   (OFF_KH + Bb*Hh*Tt*Nn*HD/2)
#define OFF_VW1  (OFF_QH + Bb*Hh*Tt*Nn*HD/2)    // f32 [b,h][t][n]
#define OFF_VW2  (OFF_VW1 + Bb*Hh*Tt*Nn)
#define OFF_E    (OFF_VW2 + Bb*Hh*Tt*Nn)        // B*N*N
#define OFF_VV   (OFF_E + Bb*Nn*Nn)             // BN*D
#define OFF_WKQ  (OFF_VV + BN*Dd)               // f16 frag [W_kc|W_qc|u]: 17408 floats
#define OFF_WT   (OFF_WKQ + 17408)              // f16 frag W_hh: 24576 floats
#define OFF_WDF  (OFF_WT + 24576)               // f16 frag W_dec: 16384 floats
#define OFF_WMF  (OFF_WDF + 16384)              // f16 frag [W_mu|W_sig]: 1024 floats
#define WS_FLOATS (OFF_WMF + 1024)

typedef _Float16 half2_t __attribute__((ext_vector_type(2)));
typedef _Float16 f16x8 __attribute__((ext_vector_type(8)));
typedef float f32x4 __attribute__((ext_vector_type(4)));

__device__ __forceinline__ float fast_sigmoid(float v) {
  return 1.f / (1.f + __expf(-v));
}
__device__ __forceinline__ float fast_tanh(float v) {
  float e2 = __expf(2.f * v);
  return 1.f - 2.f / (e2 + 1.f);
}
__device__ __forceinline__ float fdot2(uint32_t a, uint32_t b, float c) {
  half2_t av = __builtin_bit_cast(half2_t, a);
  half2_t bv = __builtin_bit_cast(half2_t, b);
#if __has_builtin(__builtin_amdgcn_fdot2)
  return __builtin_amdgcn_fdot2(av, bv, c, false);
#else
  return c + (float)av.x * (float)bv.x + (float)av.y * (float)bv.y;
#endif
}
__device__ __forceinline__ uint32_t bcast_lane(uint32_t v, int l) {
  return (uint32_t)__builtin_amdgcn_readlane((int)v, l);
}

// ---------------- kernel 0: fold weights + pack all MFMA B-fragments ----------------
// blocks: 0 fold | 1..24 W_hh | 25..41 W_kq+u | 42..49 W_dec | 50 W_mu|W_sig
__global__ __launch_bounds__(384) void k_precompute(
    const float* __restrict__ W_se, const float* __restrict__ b_se,
    const float* __restrict__ W_ih, const float* __restrict__ b_ih,
    const float* __restrict__ W_hh,
    const float* __restrict__ W_kc, const float* __restrict__ W_qc,
    const float* __restrict__ W_vc, const float* __restrict__ W_att,
    const float* __restrict__ W_dec, const float* __restrict__ W_mu,
    const float* __restrict__ W_sig,
    float* __restrict__ ws) {
  const int tid = threadIdx.x;
  if (blockIdx.x == 50) {
    _Float16* WF = (_Float16*)(ws + OFF_WMF);
    for (int idx = tid; idx < 4*64*8; idx += 384) {
      int ks = idx >> 9, l = (idx >> 3) & 63, j = idx & 7;
      int k = ks*32 + (l >> 4)*8 + j;
      int c16 = l & 15;
      float v = (c16 < 4) ? W_mu[(size_t)k*Ss + c16]
              : ((c16 < 8) ? W_sig[(size_t)k*Ss + c16 - 4] : 0.f);
      WF[(size_t)(ks*64 + l)*8 + j] = (_Float16)v;
    }
    return;
  }
  if (blockIdx.x >= 42) {
    const int nt = blockIdx.x - 42;  // 0..7
    _Float16* WF = (_Float16*)(ws + OFF_WDF);
    for (int idx = tid; idx < 8*64*8; idx += 384) {
      int ks = idx >> 9, l = (idx >> 3) & 63, j = idx & 7;
      int k = ks*32 + (l >> 4)*8 + j;         // 0..255
      int c = nt*16 + (l & 15);
      WF[(size_t)((nt*8 + ks)*64 + l)*8 + j] = (_Float16)W_dec[(size_t)k*Dd + c];
    }
    return;
  }
  if (blockIdx.x >= 25) {
    const int nt = blockIdx.x - 25;  // 0..16
    _Float16* WF = (_Float16*)(ws + OFF_WKQ);
    for (int idx = tid; idx < 4*64*8; idx += 384) {
      int ks = idx >> 9, l = (idx >> 3) & 63, j = idx & 7;
      int k = ks*32 + (l >> 4)*8 + j;
      int c16 = l & 15;
      float v;
      if (nt < 16) {
        int cg = nt*16 + c16;
        v = (cg < Dd) ? W_kc[(size_t)k*Dd + cg] : W_qc[(size_t)k*Dd + cg - Dd];
      } else {
        int h = c16 >> 1, which = c16 & 1;
        float s = 0.f;
        for (int d = 0; d < HD; ++d)
          s = fmaf(W_vc[(size_t)k*Dd + h*HD + d], W_att[which*Dd + h*HD + d], s);
        v = s;
      }
      WF[(size_t)((nt*4 + ks)*64 + l)*8 + j] = (_Float16)v;
    }
    return;
  }
  if (blockIdx.x > 0) {
    const int nt = blockIdx.x - 1;  // 0..23
    _Float16* WF = (_Float16*)(ws + OFF_WT);
    for (int idx = tid; idx < 4*64*8; idx += 384) {
      int ks = idx >> 9, l = (idx >> 3) & 63, j = idx & 7;
      int k = ks*32 + (l >> 4)*8 + j;
      int c = nt*16 + (l & 15);
      WF[(size_t)((nt*4 + ks)*64 + l)*8 + j] = (_Float16)W_hh[(size_t)k*G3 + c];
    }
    return;
  }
  const int c = tid;
  float* Wx = ws + OFF_WX; float* bx = ws + OFF_BX;
  float accb = b_ih[c];
  float a0 = 0.f, a1 = 0.f, a2 = 0.f, a3 = 0.f;
  for (int k = 0; k < Dd; ++k) {
    float w = W_ih[k*G3 + c];
    accb = fmaf(b_se[k], w, accb);
    a0 = fmaf(W_se[0*Dd + k], w, a0);
    a1 = fmaf(W_se[1*Dd + k], w, a1);
    a2 = fmaf(W_se[2*Dd + k], w, a2);
    a3 = fmaf(W_se[3*Dd + k], w, a3);
  }
  bx[c] = accb;
  Wx[0*G3 + c] = a0; Wx[1*G3 + c] = a1; Wx[2*G3 + c] = a2; Wx[3*G3 + c] = a3;
}

// ---------------- kernel 1: GRU via MFMA (f16), W fragments register-resident ----------------
__global__ __launch_bounds__(512, 2) void k_gru(
    const float* __restrict__ x, const float* __restrict__ W_init,
    const float* __restrict__ b_init,
    const float* __restrict__ b_hh, float* __restrict__ ws) {
  __shared__ __align__(16) _Float16 h_l[4][Dd + 8];
  __shared__ float gg[4][G3];
  __shared__ float xt_l[Tt+1][4][Ss];
  const int tid = threadIdx.x;
  const int wave = tid >> 6;
  const int lane = tid & 63;
  const int l15 = lane & 15;
  const int lk = lane >> 4;
  const int blk = blockIdx.x;
  const int row0 = blk * 4;
  const int b = row0 >> 6;
  const int n0 = row0 & 63;
  float* ys = ws + OFF_YS;
  const float* Wx = ws + OFF_WX;
  const float* bxp = ws + OFF_BX;

  const f16x8* WF = (const f16x8*)(ws + OFF_WT);
  f16x8 wf[3][4];
  #pragma unroll
  for (int i = 0; i < 3; ++i)
    #pragma unroll
    for (int ks = 0; ks < 4; ++ks)
      wf[i][ks] = WF[(size_t)((wave*3 + i)*4 + ks)*64 + lane];
  float br[3];
  #pragma unroll
  for (int i = 0; i < 3; ++i) br[i] = b_hh[(wave*3 + i)*16 + l15];

  const int row = tid >> 7, d = tid & 127;
  float wxr[3][4], bx3[3];
  #pragma unroll
  for (int g = 0; g < 3; ++g) {
    bx3[g] = bxp[g*Dd + d];
    #pragma unroll
    for (int s = 0; s < 4; ++s) wxr[g][s] = Wx[s*G3 + g*Dd + d];
  }

  for (int idx = tid; idx < (Tt+1)*4*Ss; idx += 512) {
    int t = idx >> 4, r = (idx >> 2) & 3, s = idx & 3;
    xt_l[t][r][s] = x[((size_t)(b*(Tt+1) + t)*Nn + (n0 + r))*Ss + s];
  }
  __syncthreads();

  float hprev;
  {
    float h0 = b_init[d];
    #pragma unroll
    for (int s = 0; s < Ss; ++s)
      h0 = fmaf(xt_l[0][row][s], W_init[s*Dd + d], h0);
    hprev = h0;
    h_l[row][d] = (_Float16)h0;
  }
  __syncthreads();

  for (int t = 0; t < Tt; ++t) {
    f16x8 af[4];
    #pragma unroll
    for (int ks = 0; ks < 4; ++ks)
      af[ks] = *(const f16x8*)&h_l[l15 & 3][ks*32 + lk*8];
    #pragma unroll
    for (int i = 0; i < 3; ++i) {
      f32x4 acc = {br[i], br[i], br[i], br[i]};
      #pragma unroll
      for (int ks = 0; ks < 4; ++ks)
        acc = __builtin_amdgcn_mfma_f32_16x16x32_f16(af[ks], wf[i][ks], acc, 0, 0, 0);
      if (lane < 16) {
        const int col = (wave*3 + i)*16 + l15;
        gg[0][col] = acc[0];
        gg[1][col] = acc[1];
        gg[2][col] = acc[2];
        gg[3][col] = acc[3];
      }
    }
    __syncthreads();
    {
      float gi_r = bx3[0], gi_z = bx3[1], gi_n = bx3[2];
      #pragma unroll
      for (int s = 0; s < 4; ++s) {
        float xv = xt_l[t][row][s];
        gi_r = fmaf(xv, wxr[0][s], gi_r);
        gi_z = fmaf(xv, wxr[1][s], gi_z);
        gi_n = fmaf(xv, wxr[2][s], gi_n);
      }
      float rg = fast_sigmoid(gi_r + gg[row][d]);
      float zg = fast_sigmoid(gi_z + gg[row][Dd + d]);
      float ng = fast_tanh(fmaf(rg, gg[row][2*Dd + d], gi_n));
      float hnew = fmaf(zg, hprev - ng, ng);
      hprev = hnew;
      h_l[row][d] = (_Float16)hnew;
      ys[(size_t)(t*BN + row0 + row)*Dd + d] = hnew;
    }
    __syncthreads();
  }
}

// ---------------- kernel 2: k,q,vw via MFMA (f16); K/Q written f16 head-major ----------------
__global__ __launch_bounds__(256, 2) void k_kqv(float* __restrict__ ws) {
  __shared__ __align__(16) _Float16 ysl[64][136];
  const int tid = threadIdx.x;
  const int blk = blockIdx.x;    // b*T + t
  const int b = blk >> 6, t = blk & 63;
  const int wave = tid >> 6, lane = tid & 63;
  const int l15 = lane & 15, lk = lane >> 4;

  const f16x8* WKQ = (const f16x8*)(ws + OFF_WKQ);
  f16x8 bf0[4], bf1[4], bf2[4], bf3[4], bu[4];
  #pragma unroll
  for (int ks = 0; ks < 4; ++ks) {
    bf0[ks] = WKQ[(size_t)((wave*4 + 0)*4 + ks)*64 + lane];
    bf1[ks] = WKQ[(size_t)((wave*4 + 1)*4 + ks)*64 + lane];
    bf2[ks] = WKQ[(size_t)((wave*4 + 2)*4 + ks)*64 + lane];
    bf3[ks] = WKQ[(size_t)((wave*4 + 3)*4 + ks)*64 + lane];
    bu[ks]  = WKQ[(size_t)(16*4 + ks)*64 + lane];
  }

  const float* ysrc = ws + OFF_YS + ((size_t)t*BN + b*64)*Dd;
  for (int idx = tid; idx < 64*16; idx += 256) {
    int r = idx >> 4, k8 = (idx & 15) * 8;
    float4 v0 = *(const float4*)&ysrc[r*Dd + k8];
    float4 v1 = *(const float4*)&ysrc[r*Dd + k8 + 4];
    f16x8 hv;
    hv[0] = (_Float16)v0.x; hv[1] = (_Float16)v0.y;
    hv[2] = (_Float16)v0.z; hv[3] = (_Float16)v0.w;
    hv[4] = (_Float16)v1.x; hv[5] = (_Float16)v1.y;
    hv[6] = (_Float16)v1.z; hv[7] = (_Float16)v1.w;
    *(f16x8*)&ysl[r][k8] = hv;
  }
  __syncthreads();

  _Float16* khd = (_Float16*)(ws + OFF_KH);
  _Float16* qhd = (_Float16*)(ws + OFF_QH);

  #pragma unroll
  for (int mt = 0; mt < 4; ++mt) {
    f16x8 af[4];
    #pragma unroll
    for (int ks = 0; ks < 4; ++ks)
      af[ks] = *(const f16x8*)&ysl[mt*16 + l15][ks*32 + lk*8];
    f32x4 a0 = {0.f,0.f,0.f,0.f}, a1 = a0, a2 = a0, a3 = a0;
    #pragma unroll
    for (int ks = 0; ks < 4; ++ks) {
      a0 = __builtin_amdgcn_mfma_f32_16x16x32_f16(af[ks], bf0[ks], a0, 0, 0, 0);
      a1 = __builtin_amdgcn_mfma_f32_16x16x32_f16(af[ks], bf1[ks], a1, 0, 0, 0);
      a2 = __builtin_amdgcn_mfma_f32_16x16x32_f16(af[ks], bf2[ks], a2, 0, 0, 0);
      a3 = __builtin_amdgcn_mfma_f32_16x16x32_f16(af[ks], bf3[ks], a3, 0, 0, 0);
    }
    const int rowb = mt*16 + lk*4;
    #pragma unroll
    for (int nti = 0; nti < 4; ++nti) {
      f32x4 av = (nti == 0) ? a0 : (nti == 1) ? a1 : (nti == 2) ? a2 : a3;
      const int gc = wave*64 + nti*16 + l15;
      const int hh = (gc >> 4) & 7;
      const int dd2 = gc & 15;
      _Float16* base = (gc < Dd) ? khd : qhd;
      const size_t rowbase = ((size_t)(b*Hh + hh)*Tt + t)*Nn*HD;
      #pragma unroll
      for (int rg2 = 0; rg2 < 4; ++rg2)
        base[rowbase + (size_t)(rowb + rg2)*HD + dd2] = (_Float16)av[rg2];
    }
    if (wave == 3) {
      f32x4 au = {0.f,0.f,0.f,0.f};
      #pragma unroll
      for (int ks = 0; ks < 4; ++ks)
        au = __builtin_amdgcn_mfma_f32_16x16x32_f16(af[ks], bu[ks], au, 0, 0, 0);
      const int h = l15 >> 1, which = l15 & 1;
      float* vw = ws + (which ? OFF_VW2 : OFF_VW1) + ((size_t)(b*Hh + h)*Tt + t)*Nn;
      #pragma unroll
      for (int rg2 = 0; rg2 < 4; ++rg2)
        vw[rowb + rg2] = au[rg2];
    }
  }
}

// ---------------- kernel 3: attn — clamp-exp softmax, 2 blocks/CU ----------------
__global__ __launch_bounds__(512) void k_attn(float* __restrict__ ws) {
  __shared__ __align__(16) uint32_t k_l[TT][16][8];   // 4 KB
  __shared__ __align__(8) uint2 q_l2[TT][4][64];      // 16 KB
  __shared__ float vw1_l[TT][16], vw2_l[TT][16];      // 1 KB
  const int tid = threadIdx.x;
  const int blk = blockIdx.x;         // bh*4 + quarter
  const int quarter = blk & 3;
  const int bh = blk >> 2;
  const int b = bh >> 3;
  const int i0 = quarter * 16;
  const int lane = tid & 63;          // j
  const int ig = tid >> 6;            // wave 0..7 -> i pair
  const int j = lane;
  const uint32_t* kh = (const uint32_t*)((const _Float16*)(ws + OFF_KH) + (size_t)bh*Tt*Nn*HD);
  const uint32_t* qh = (const uint32_t*)((const _Float16*)(ws + OFF_QH) + (size_t)bh*Tt*Nn*HD);
  const float* vw1 = ws + OFF_VW1 + (size_t)bh*Tt*Nn;
  const float* vw2 = ws + OFF_VW2 + (size_t)bh*Tt*Nn;
  float* e = ws + OFF_E + (size_t)b*Nn*Nn;
  float S0 = 0.f, S1 = 0.f, A10 = 0.f, A11 = 0.f, A20 = 0.f, A21 = 0.f;
  const float scale = 0.08838834764831845f; // 1/sqrt(128)

  for (int tc = 0; tc < Tt/TT; ++tc) {
    const int tbase = tc * TT;
    __syncthreads();
    if (tid < 256) {
      int t = tid >> 5, il = (tid >> 1) & 15, d4 = tid & 1;
      *(uint4*)&k_l[t][il][d4*4] =
          *(const uint4*)&kh[((size_t)(tbase + t)*Nn + i0 + il)*8 + d4*4];
    }
    #pragma unroll
    for (int s = 0; s < 2; ++s) {
      int fi = tid + s*512;
      int t = fi >> 7, r = fi & 127;
      int jj = r >> 1, h4 = (r & 1)*4;
      uint4 v = *(const uint4*)&qh[((size_t)(tbase + t)*Nn + jj)*8 + h4];
      q_l2[t][(h4 >> 1) + 0][jj] = make_uint2(v.x, v.y);
      q_l2[t][(h4 >> 1) + 1][jj] = make_uint2(v.z, v.w);
    }
    if (tid < 256) {
      int which = tid >> 7, t = (tid >> 4) & 7, il = tid & 15;
      float v = (which ? vw2 : vw1)[(size_t)(tbase + t)*Nn + i0 + il];
      if (which) vw2_l[t][il] = v; else vw1_l[t][il] = v;
    }
    __syncthreads();

    for (int tt = 0; tt < TT; ++tt) {
      uint2 kp = ((const uint2*)&k_l[tt][0][0])[lane];
      uint2 q0 = q_l2[tt][0][j];
      uint2 q1 = q_l2[tt][1][j];
      uint2 q2 = q_l2[tt][2][j];
      uint2 q3 = q_l2[tt][3][j];
      float2 v1 = *(const float2*)&vw1_l[tt][ig*2];
      float2 v2 = *(const float2*)&vw2_l[tt][ig*2];
      #pragma unroll
      for (int p = 0; p < 2; ++p) {
        const int base = (ig*2 + p)*4;
        float s = 0.f;
        s = fdot2(bcast_lane(kp.x, base+0), q0.x, s);
        s = fdot2(bcast_lane(kp.y, base+0), q0.y, s);
        s = fdot2(bcast_lane(kp.x, base+1), q1.x, s);
        s = fdot2(bcast_lane(kp.y, base+1), q1.y, s);
        s = fdot2(bcast_lane(kp.x, base+2), q2.x, s);
        s = fdot2(bcast_lane(kp.y, base+2), q2.y, s);
        s = fdot2(bcast_lane(kp.x, base+3), q3.x, s);
        s = fdot2(bcast_lane(kp.y, base+3), q3.y, s);
        s = fminf(fmaxf(s * scale, -60.f), 60.f);
        float ee = __expf(s);
        if (p == 0) {
          S0 += ee; A10 = fmaf(ee, v1.x, A10); A20 = fmaf(ee, v2.x, A20);
        } else {
          S1 += ee; A11 = fmaf(ee, v1.y, A11); A21 = fmaf(ee, v2.y, A21);
        }
      }
    }
  }
  {
    const int i = i0 + ig*2;
    float inv0 = 1.f / S0, inv1 = 1.f / S1;
    atomicAdd(&e[i*Nn + j], A10 * inv0);
    atomicAdd(&e[j*Nn + i], A20 * inv0);
    atomicAdd(&e[(i+1)*Nn + j], A11 * inv1);
    atomicAdd(&e[j*Nn + i + 1], A21 * inv1);
  }
}

// ---------------- kernel 4: decode GRU step + vv ----------------
__global__ __launch_bounds__(384) void k_decode(
    const float* __restrict__ x, const float* __restrict__ W_hh,
    const float* __restrict__ b_hh, const float* __restrict__ W_val,
    const float* __restrict__ b_val, float* __restrict__ ws) {
  __shared__ float h_lds[4][Dd];
  __shared__ float g_lds[4][4*Dd];
  __shared__ float xt[4][Ss];
  const int tid = threadIdx.x;
  const int blk = blockIdx.x;
  const int row0 = blk * 4;
  const int b = row0 >> 6;
  const int n0 = row0 & 63;
  const float* ys = ws + OFF_YS;
  const float* Wx = ws + OFF_WX;
  const float* bxp = ws + OFF_BX;
  if (tid < Dd) {
    for (int r = 0; r < 4; ++r)
      h_lds[r][tid] = ys[(size_t)((Tt-1)*BN + row0 + r)*Dd + tid];
  }
  if (tid >= 320 && tid < 336) {
    int q = tid - 320; int r = q >> 2, s = q & 3;
    xt[r][s] = x[((size_t)(b*(Tt+1) + Tt)*Nn + (n0 + r))*Ss + s];
  }
  const int c = tid;
  const float bhh = b_hh[c];
  const float wx0 = Wx[0*G3 + c], wx1 = Wx[1*G3 + c], wx2 = Wx[2*G3 + c], wx3 = Wx[3*G3 + c];
  const float bxv = bxp[c];
  __syncthreads();
  float acc[4] = {bhh, bhh, bhh, bhh};
  for (int k = 0; k < Dd; k += 4) {
    float w0 = W_hh[(k+0)*G3 + c];
    float w1 = W_hh[(k+1)*G3 + c];
    float w2 = W_hh[(k+2)*G3 + c];
    float w3 = W_hh[(k+3)*G3 + c];
    #pragma unroll
    for (int r = 0; r < 4; ++r) {
      float4 hv = *(const float4*)&h_lds[r][k];
      acc[r] = fmaf(hv.x, w0, acc[r]);
      acc[r] = fmaf(hv.y, w1, acc[r]);
      acc[r] = fmaf(hv.z, w2, acc[r]);
      acc[r] = fmaf(hv.w, w3, acc[r]);
    }
  }
  float gi[4];
  #pragma unroll
  for (int r = 0; r < 4; ++r) {
    float g = bxv;
    g = fmaf(xt[r][0], wx0, g);
    g = fmaf(xt[r][1], wx1, g);
    g = fmaf(xt[r][2], wx2, g);
    g = fmaf(xt[r][3], wx3, g);
    gi[r] = g;
  }
  if (c < 2*Dd) {
    #pragma unroll
    for (int r = 0; r < 4; ++r) g_lds[r][c] = acc[r] + gi[r];
  } else {
    #pragma unroll
    for (int r = 0; r < 4; ++r) { g_lds[r][c] = gi[r]; g_lds[r][c + Dd] = acc[r]; }
  }
  __syncthreads();
  if (tid < Dd) {
    const int d = tid;
    #pragma unroll
    for (int r = 0; r < 4; ++r) {
      float rg = fast_sigmoid(g_lds[r][d]);
      float zg = fast_sigmoid(g_lds[r][Dd + d]);
      float ng = fast_tanh(fmaf(rg, g_lds[r][3*Dd + d], g_lds[r][2*Dd + d]));
      float hn = fmaf(zg, h_lds[r][d] - ng, ng);
      h_lds[r][d] = hn;
    }
  }
  __syncthreads();
  if (tid < Dd) {
    const int c2 = tid;
    for (int r = 0; r < 4; ++r) {
      float a = b_val[c2];
      for (int k = 0; k < Dd; k += 4) {
        float4 hv = *(const float4*)&h_lds[r][k];
        a = fmaf(hv.x, W_val[(k+0)*Dd + c2], a);
        a = fmaf(hv.y, W_val[(k+1)*Dd + c2], a);
        a = fmaf(hv.z, W_val[(k+2)*Dd + c2], a);
        a = fmaf(hv.w, W_val[(k+3)*Dd + c2], a);
      }
      ws[OFF_VV + (size_t)(row0 + r)*Dd + c2] = a;
    }
  }
}

// ---------------- kernel 5: weight/p/dec/mu/sig — all via MFMA ----------------
// block = (b, i-quarter): M=16 rows. p-GEMM (w@vv), d-GEMM ([vv|p]@W_dec frags),
// head-GEMM (d@[W_mu|W_sig] frags). Replaces the 2048-iter serial L2 chain.
__global__ __launch_bounds__(256) void k_final(
    const float* __restrict__ b_dec, const float* __restrict__ b_mu,
    const float* __restrict__ b_sig, const float* __restrict__ b_att,
    float* __restrict__ ws, float* __restrict__ out) {
  __shared__ __align__(16) _Float16 vvT[Dd][72];   // B for p-GEMM (transposed)
  __shared__ __align__(16) _Float16 wl[16][72];    // A for p-GEMM
  __shared__ __align__(16) _Float16 A2[16][264];   // A for d-GEMM: [vv_i | p]
  __shared__ __align__(16) _Float16 A3[16][136];   // d rows
  const int tid = threadIdx.x;
  const int wave = tid >> 6, lane = tid & 63;
  const int l15 = lane & 15, lk = lane >> 4;
  const int blk = blockIdx.x;
  const int b = blk >> 2, iq = blk & 3, i0 = iq*16;
  const float* vv = ws + OFF_VV + (size_t)b*64*Dd;
  const float* e  = ws + OFF_E + (size_t)b*Nn*Nn;
  const float batt = b_att[0];

  // stage vvT (f16 transposed) + A2 vv rows (our 16 i's)
  for (int idx = tid; idx < 64*Dd/4; idx += 256) {
    int r = idx >> 5, k4 = (idx & 31)*4;
    float4 v = *(const float4*)&vv[r*Dd + k4];
    vvT[k4+0][r] = (_Float16)v.x;
    vvT[k4+1][r] = (_Float16)v.y;
    vvT[k4+2][r] = (_Float16)v.z;
    vvT[k4+3][r] = (_Float16)v.w;
    int rl = r - i0;
    if (rl >= 0 && rl < 16) {
      A2[rl][k4+0] = (_Float16)v.x;
      A2[rl][k4+1] = (_Float16)v.y;
      A2[rl][k4+2] = (_Float16)v.z;
      A2[rl][k4+3] = (_Float16)v.w;
    }
  }
  // w rows (tanh, zero diag)
  for (int idx = tid; idx < 16*64; idx += 256) {
    int il = idx >> 6, jj = idx & 63;
    int i = i0 + il;
    float v = (i == jj) ? 0.f : fast_tanh(e[i*Nn + jj] + batt + 0.5f);
    wl[il][jj] = (_Float16)v;
  }
  __syncthreads();

  // p-GEMM: wave owns d-tiles wave*2, wave*2+1; K=64 (2 ksteps)
  {
    f16x8 a0 = *(const f16x8*)&wl[l15][lk*8];
    f16x8 a1 = *(const f16x8*)&wl[l15][32 + lk*8];
    #pragma unroll
    for (int q = 0; q < 2; ++q) {
      const int nt = wave*2 + q;
      f16x8 b0 = *(const f16x8*)&vvT[nt*16 + l15][lk*8];
      f16x8 b1 = *(const f16x8*)&vvT[nt*16 + l15][32 + lk*8];
      f32x4 acc = {0.f,0.f,0.f,0.f};
      acc = __builtin_amdgcn_mfma_f32_16x16x32_f16(a0, b0, acc, 0, 0, 0);
      acc = __builtin_amdgcn_mfma_f32_16x16x32_f16(a1, b1, acc, 0, 0, 0);
      #pragma unroll
      for (int r = 0; r < 4; ++r)
        A2[lk*4 + r][128 + nt*16 + l15] = (_Float16)(acc[r] * (1.f/64.f));
    }
  }
  __syncthreads();

  // d-GEMM: K=256 (8 ksteps); wave owns e-col tiles wave*2, wave*2+1
  const f16x8* WDF = (const f16x8*)(ws + OFF_WDF);
  {
    f16x8 ad[8];
    #pragma unroll
    for (int ks = 0; ks < 8; ++ks)
      ad[ks] = *(const f16x8*)&A2[l15][ks*32 + lk*8];
    #pragma unroll
    for (int q = 0; q < 2; ++q) {
      const int nt = wave*2 + q;
      const float bias = b_dec[nt*16 + l15];
      f32x4 acc = {bias, bias, bias, bias};
      #pragma unroll
      for (int ks = 0; ks < 8; ++ks)
        acc = __builtin_amdgcn_mfma_f32_16x16x32_f16(
            ad[ks], WDF[(size_t)((nt*8 + ks)*64) + lane], acc, 0, 0, 0);
      #pragma unroll
      for (int r = 0; r < 4; ++r)
        A3[lk*4 + r][nt*16 + l15] = (_Float16)acc[r];
    }
  }
  __syncthreads();

  // head-GEMM on wave 0: [16x128] @ [128x8] (mu cols 0-3, sig cols 4-7)
  if (wave == 0) {
    const f16x8* WMF = (const f16x8*)(ws + OFF_WMF);
    f16x8 ah[4];
    #pragma unroll
    for (int ks = 0; ks < 4; ++ks)
      ah[ks] = *(const f16x8*)&A3[l15][ks*32 + lk*8];
    const float bias = (l15 < 4) ? b_mu[l15] : ((l15 < 8) ? b_sig[l15 - 4] : 0.f);
    f32x4 acc = {bias, bias, bias, bias};
    #pragma unroll
    for (int ks = 0; ks < 4; ++ks)
      acc = __builtin_amdgcn_mfma_f32_16x16x32_f16(
          ah[ks], WMF[(size_t)(ks*64) + lane], acc, 0, 0, 0);
    if (l15 < 8) {
      const int which = l15 >> 2, s = l15 & 3;
      #pragma unroll
      for (int r = 0; r < 4; ++r) {
        float v = acc[r];
        if (which) v = 1.f/(1.f + __expf(-v)) + 1e-6f;
        out[(size_t)which*(Bb*Nn*Ss) + (size_t)(b*64 + i0 + lk*4 + r)*Ss + s] = v;
      }
    }
  }
}

extern "C" void kernel_launch(void* const* d_in, const int* in_sizes, int n_in,
                              void* d_out, int out_size, void* d_ws, size_t ws_size,
                              hipStream_t stream) {
  const float* x     = (const float*)d_in[0];
  const float* W_se  = (const float*)d_in[1];
  const float* b_se  = (const float*)d_in[2];
  const float* W_init= (const float*)d_in[3];
  const float* b_init= (const float*)d_in[4];
  const float* W_ih  = (const float*)d_in[5];
  const float* W_hh  = (const float*)d_in[6];
  const float* b_ih  = (const float*)d_in[7];
  const float* b_hh  = (const float*)d_in[8];
  const float* W_kc  = (const float*)d_in[9];
  const float* W_qc  = (const float*)d_in[10];
  const float* W_vc  = (const float*)d_in[11];
  const float* W_att = (const float*)d_in[12];
  const float* b_att = (const float*)d_in[13];
  const float* W_val = (const float*)d_in[14];
  const float* b_val = (const float*)d_in[15];
  const float* W_dec = (const float*)d_in[16];
  const float* b_dec = (const float*)d_in[17];
  const float* W_mu  = (const float*)d_in[18];
  const float* b_mu  = (const float*)d_in[19];
  const float* W_sig = (const float*)d_in[20];
  const float* b_sig = (const float*)d_in[21];
  float* ws = (float*)d_ws;
  float* out = (float*)d_out;

  if (ws_size < (size_t)WS_FLOATS * sizeof(float)) return;

  hipMemsetAsync(ws + OFF_E, 0, (size_t)Bb*Nn*Nn*sizeof(float), stream);
  k_precompute<<<51, 384, 0, stream>>>(W_se, b_se, W_ih, b_ih, W_hh, W_kc, W_qc,
                                       W_vc, W_att, W_dec, W_mu, W_sig, ws);
  k_gru<<<BN/4, 512, 0, stream>>>(x, W_init, b_init, b_hh, ws);
  k_kqv<<<Bb*Tt, 256, 0, stream>>>(ws);
  k_attn<<<Bb*Hh*4, 512, 0, stream>>>(ws);
  k_decode<<<BN/4, 384, 0, stream>>>(x, W_hh, b_hh, W_val, b_val, ws);
  k_final<<<Bb*4, 256, 0, stream>>>(b_dec, b_mu, b_sig, b_att, ws, out);
}

// Round 15
// 162.005 us; speedup vs baseline: 1.3788x; 1.0485x over previous
//
#include <hip/hip_runtime.h>
#include <math.h>

#define Bb 16
#define Tt 64
#define Nn 64
#define Ss 4
#define Dd 128
#define Hh 8
#define HD 16
#define BN 1024
#define G3 384   // 3*D
#define TT 8

// workspace layout (in floats)
#define OFF_WX   0                              // 4*384
#define OFF_BX   1536                           // 384
#define OFF_YS   4096                           // T*BN*D
#define OFF_KH   (OFF_YS + Tt*BN*Dd)            // f16 [b,h][t][n][16]
#define OFF_QH   (OFF_KH + Bb*Hh*Tt*Nn*HD/2)
#define OFF_VW1  (OFF_QH + Bb*Hh*Tt*Nn*HD/2)    // f32 [b,h][t][n]
#define OFF_VW2  (OFF_VW1 + Bb*Hh*Tt*Nn)
#define OFF_E    (OFF_VW2 + Bb*Hh*Tt*Nn)        // B*N*N
#define OFF_VV   (OFF_E + Bb*Nn*Nn)             // BN*D
#define OFF_WKQ  (OFF_VV + BN*Dd)               // f16 frag [W_kc|W_qc|u]: 17408 floats
#define OFF_WT   (OFF_WKQ + 17408)              // f16 frag W_hh: 24576 floats
#define OFF_WDF  (OFF_WT + 24576)               // f16 frag W_dec: 16384 floats
#define OFF_WMF  (OFF_WDF + 16384)              // f16 frag [W_mu|W_sig]: 1024 floats
#define WS_FLOATS (OFF_WMF + 1024)

typedef _Float16 half2_t __attribute__((ext_vector_type(2)));
typedef _Float16 f16x8 __attribute__((ext_vector_type(8)));
typedef float f32x4 __attribute__((ext_vector_type(4)));

__device__ __forceinline__ float fast_sigmoid(float v) {
  return 1.f / (1.f + __expf(-v));
}
__device__ __forceinline__ float fast_tanh(float v) {
  float e2 = __expf(2.f * v);
  return 1.f - 2.f / (e2 + 1.f);
}
__device__ __forceinline__ float fdot2(uint32_t a, uint32_t b, float c) {
  half2_t av = __builtin_bit_cast(half2_t, a);
  half2_t bv = __builtin_bit_cast(half2_t, b);
#if __has_builtin(__builtin_amdgcn_fdot2)
  return __builtin_amdgcn_fdot2(av, bv, c, false);
#else
  return c + (float)av.x * (float)bv.x + (float)av.y * (float)bv.y;
#endif
}
__device__ __forceinline__ uint32_t bcast_lane(uint32_t v, int l) {
  return (uint32_t)__builtin_amdgcn_readlane((int)v, l);
}

// ---------------- kernel 0: fold weights + pack all MFMA B-fragments ----------------
__global__ __launch_bounds__(384) void k_precompute(
    const float* __restrict__ W_se, const float* __restrict__ b_se,
    const float* __restrict__ W_ih, const float* __restrict__ b_ih,
    const float* __restrict__ W_hh,
    const float* __restrict__ W_kc, const float* __restrict__ W_qc,
    const float* __restrict__ W_vc, const float* __restrict__ W_att,
    const float* __restrict__ W_dec, const float* __restrict__ W_mu,
    const float* __restrict__ W_sig,
    float* __restrict__ ws) {
  const int tid = threadIdx.x;
  if (blockIdx.x == 50) {
    _Float16* WF = (_Float16*)(ws + OFF_WMF);
    for (int idx = tid; idx < 4*64*8; idx += 384) {
      int ks = idx >> 9, l = (idx >> 3) & 63, j = idx & 7;
      int k = ks*32 + (l >> 4)*8 + j;
      int c16 = l & 15;
      float v = (c16 < 4) ? W_mu[(size_t)k*Ss + c16]
              : ((c16 < 8) ? W_sig[(size_t)k*Ss + c16 - 4] : 0.f);
      WF[(size_t)(ks*64 + l)*8 + j] = (_Float16)v;
    }
    return;
  }
  if (blockIdx.x >= 42) {
    const int nt = blockIdx.x - 42;  // 0..7
    _Float16* WF = (_Float16*)(ws + OFF_WDF);
    for (int idx = tid; idx < 8*64*8; idx += 384) {
      int ks = idx >> 9, l = (idx >> 3) & 63, j = idx & 7;
      int k = ks*32 + (l >> 4)*8 + j;
      int c = nt*16 + (l & 15);
      WF[(size_t)((nt*8 + ks)*64 + l)*8 + j] = (_Float16)W_dec[(size_t)k*Dd + c];
    }
    return;
  }
  if (blockIdx.x >= 25) {
    const int nt = blockIdx.x - 25;  // 0..16
    _Float16* WF = (_Float16*)(ws + OFF_WKQ);
    for (int idx = tid; idx < 4*64*8; idx += 384) {
      int ks = idx >> 9, l = (idx >> 3) & 63, j = idx & 7;
      int k = ks*32 + (l >> 4)*8 + j;
      int c16 = l & 15;
      float v;
      if (nt < 16) {
        int cg = nt*16 + c16;
        v = (cg < Dd) ? W_kc[(size_t)k*Dd + cg] : W_qc[(size_t)k*Dd + cg - Dd];
      } else {
        int h = c16 >> 1, which = c16 & 1;
        float s = 0.f;
        for (int d = 0; d < HD; ++d)
          s = fmaf(W_vc[(size_t)k*Dd + h*HD + d], W_att[which*Dd + h*HD + d], s);
        v = s;
      }
      WF[(size_t)((nt*4 + ks)*64 + l)*8 + j] = (_Float16)v;
    }
    return;
  }
  if (blockIdx.x > 0) {
    const int nt = blockIdx.x - 1;  // 0..23
    _Float16* WF = (_Float16*)(ws + OFF_WT);
    for (int idx = tid; idx < 4*64*8; idx += 384) {
      int ks = idx >> 9, l = (idx >> 3) & 63, j = idx & 7;
      int k = ks*32 + (l >> 4)*8 + j;
      int c = nt*16 + (l & 15);
      WF[(size_t)((nt*4 + ks)*64 + l)*8 + j] = (_Float16)W_hh[(size_t)k*G3 + c];
    }
    return;
  }
  const int c = tid;
  float* Wx = ws + OFF_WX; float* bx = ws + OFF_BX;
  float accb = b_ih[c];
  float a0 = 0.f, a1 = 0.f, a2 = 0.f, a3 = 0.f;
  for (int k = 0; k < Dd; ++k) {
    float w = W_ih[k*G3 + c];
    accb = fmaf(b_se[k], w, accb);
    a0 = fmaf(W_se[0*Dd + k], w, a0);
    a1 = fmaf(W_se[1*Dd + k], w, a1);
    a2 = fmaf(W_se[2*Dd + k], w, a2);
    a3 = fmaf(W_se[3*Dd + k], w, a3);
  }
  bx[c] = accb;
  Wx[0*G3 + c] = a0; Wx[1*G3 + c] = a1; Wx[2*G3 + c] = a2; Wx[3*G3 + c] = a3;
}

// ---------------- kernel 1: GRU via MFMA (f16), W fragments register-resident ----------------
__global__ __launch_bounds__(512, 2) void k_gru(
    const float* __restrict__ x, const float* __restrict__ W_init,
    const float* __restrict__ b_init,
    const float* __restrict__ b_hh, float* __restrict__ ws) {
  __shared__ __align__(16) _Float16 h_l[4][Dd + 8];
  __shared__ float gg[4][G3];
  __shared__ float xt_l[Tt+1][4][Ss];
  const int tid = threadIdx.x;
  const int wave = tid >> 6;
  const int lane = tid & 63;
  const int l15 = lane & 15;
  const int lk = lane >> 4;
  const int blk = blockIdx.x;
  const int row0 = blk * 4;
  const int b = row0 >> 6;
  const int n0 = row0 & 63;
  float* ys = ws + OFF_YS;
  const float* Wx = ws + OFF_WX;
  const float* bxp = ws + OFF_BX;

  const f16x8* WF = (const f16x8*)(ws + OFF_WT);
  f16x8 wf[3][4];
  #pragma unroll
  for (int i = 0; i < 3; ++i)
    #pragma unroll
    for (int ks = 0; ks < 4; ++ks)
      wf[i][ks] = WF[(size_t)((wave*3 + i)*4 + ks)*64 + lane];
  float br[3];
  #pragma unroll
  for (int i = 0; i < 3; ++i) br[i] = b_hh[(wave*3 + i)*16 + l15];

  const int row = tid >> 7, d = tid & 127;
  float wxr[3][4], bx3[3];
  #pragma unroll
  for (int g = 0; g < 3; ++g) {
    bx3[g] = bxp[g*Dd + d];
    #pragma unroll
    for (int s = 0; s < 4; ++s) wxr[g][s] = Wx[s*G3 + g*Dd + d];
  }

  for (int idx = tid; idx < (Tt+1)*4*Ss; idx += 512) {
    int t = idx >> 4, r = (idx >> 2) & 3, s = idx & 3;
    xt_l[t][r][s] = x[((size_t)(b*(Tt+1) + t)*Nn + (n0 + r))*Ss + s];
  }
  __syncthreads();

  float hprev;
  {
    float h0 = b_init[d];
    #pragma unroll
    for (int s = 0; s < Ss; ++s)
      h0 = fmaf(xt_l[0][row][s], W_init[s*Dd + d], h0);
    hprev = h0;
    h_l[row][d] = (_Float16)h0;
  }
  __syncthreads();

  for (int t = 0; t < Tt; ++t) {
    f16x8 af[4];
    #pragma unroll
    for (int ks = 0; ks < 4; ++ks)
      af[ks] = *(const f16x8*)&h_l[l15 & 3][ks*32 + lk*8];
    #pragma unroll
    for (int i = 0; i < 3; ++i) {
      f32x4 acc = {br[i], br[i], br[i], br[i]};
      #pragma unroll
      for (int ks = 0; ks < 4; ++ks)
        acc = __builtin_amdgcn_mfma_f32_16x16x32_f16(af[ks], wf[i][ks], acc, 0, 0, 0);
      if (lane < 16) {
        const int col = (wave*3 + i)*16 + l15;
        gg[0][col] = acc[0];
        gg[1][col] = acc[1];
        gg[2][col] = acc[2];
        gg[3][col] = acc[3];
      }
    }
    __syncthreads();
    {
      float gi_r = bx3[0], gi_z = bx3[1], gi_n = bx3[2];
      #pragma unroll
      for (int s = 0; s < 4; ++s) {
        float xv = xt_l[t][row][s];
        gi_r = fmaf(xv, wxr[0][s], gi_r);
        gi_z = fmaf(xv, wxr[1][s], gi_z);
        gi_n = fmaf(xv, wxr[2][s], gi_n);
      }
      float rg = fast_sigmoid(gi_r + gg[row][d]);
      float zg = fast_sigmoid(gi_z + gg[row][Dd + d]);
      float ng = fast_tanh(fmaf(rg, gg[row][2*Dd + d], gi_n));
      float hnew = fmaf(zg, hprev - ng, ng);
      hprev = hnew;
      h_l[row][d] = (_Float16)hnew;
      ys[(size_t)(t*BN + row0 + row)*Dd + d] = hnew;
    }
    __syncthreads();
  }
}

// ---------------- kernel 2: k,q,vw via MFMA (f16); K/Q written f16 head-major ----------------
__global__ __launch_bounds__(256, 2) void k_kqv(float* __restrict__ ws) {
  __shared__ __align__(16) _Float16 ysl[64][136];
  const int tid = threadIdx.x;
  const int blk = blockIdx.x;    // b*T + t
  const int b = blk >> 6, t = blk & 63;
  const int wave = tid >> 6, lane = tid & 63;
  const int l15 = lane & 15, lk = lane >> 4;

  const f16x8* WKQ = (const f16x8*)(ws + OFF_WKQ);
  f16x8 bf0[4], bf1[4], bf2[4], bf3[4], bu[4];
  #pragma unroll
  for (int ks = 0; ks < 4; ++ks) {
    bf0[ks] = WKQ[(size_t)((wave*4 + 0)*4 + ks)*64 + lane];
    bf1[ks] = WKQ[(size_t)((wave*4 + 1)*4 + ks)*64 + lane];
    bf2[ks] = WKQ[(size_t)((wave*4 + 2)*4 + ks)*64 + lane];
    bf3[ks] = WKQ[(size_t)((wave*4 + 3)*4 + ks)*64 + lane];
    bu[ks]  = WKQ[(size_t)(16*4 + ks)*64 + lane];
  }

  const float* ysrc = ws + OFF_YS + ((size_t)t*BN + b*64)*Dd;
  for (int idx = tid; idx < 64*16; idx += 256) {
    int r = idx >> 4, k8 = (idx & 15) * 8;
    float4 v0 = *(const float4*)&ysrc[r*Dd + k8];
    float4 v1 = *(const float4*)&ysrc[r*Dd + k8 + 4];
    f16x8 hv;
    hv[0] = (_Float16)v0.x; hv[1] = (_Float16)v0.y;
    hv[2] = (_Float16)v0.z; hv[3] = (_Float16)v0.w;
    hv[4] = (_Float16)v1.x; hv[5] = (_Float16)v1.y;
    hv[6] = (_Float16)v1.z; hv[7] = (_Float16)v1.w;
    *(f16x8*)&ysl[r][k8] = hv;
  }
  __syncthreads();

  _Float16* khd = (_Float16*)(ws + OFF_KH);
  _Float16* qhd = (_Float16*)(ws + OFF_QH);

  #pragma unroll
  for (int mt = 0; mt < 4; ++mt) {
    f16x8 af[4];
    #pragma unroll
    for (int ks = 0; ks < 4; ++ks)
      af[ks] = *(const f16x8*)&ysl[mt*16 + l15][ks*32 + lk*8];
    f32x4 a0 = {0.f,0.f,0.f,0.f}, a1 = a0, a2 = a0, a3 = a0;
    #pragma unroll
    for (int ks = 0; ks < 4; ++ks) {
      a0 = __builtin_amdgcn_mfma_f32_16x16x32_f16(af[ks], bf0[ks], a0, 0, 0, 0);
      a1 = __builtin_amdgcn_mfma_f32_16x16x32_f16(af[ks], bf1[ks], a1, 0, 0, 0);
      a2 = __builtin_amdgcn_mfma_f32_16x16x32_f16(af[ks], bf2[ks], a2, 0, 0, 0);
      a3 = __builtin_amdgcn_mfma_f32_16x16x32_f16(af[ks], bf3[ks], a3, 0, 0, 0);
    }
    const int rowb = mt*16 + lk*4;
    #pragma unroll
    for (int nti = 0; nti < 4; ++nti) {
      f32x4 av = (nti == 0) ? a0 : (nti == 1) ? a1 : (nti == 2) ? a2 : a3;
      const int gc = wave*64 + nti*16 + l15;
      const int hh = (gc >> 4) & 7;
      const int dd2 = gc & 15;
      _Float16* base = (gc < Dd) ? khd : qhd;
      const size_t rowbase = ((size_t)(b*Hh + hh)*Tt + t)*Nn*HD;
      #pragma unroll
      for (int rg2 = 0; rg2 < 4; ++rg2)
        base[rowbase + (size_t)(rowb + rg2)*HD + dd2] = (_Float16)av[rg2];
    }
    if (wave == 3) {
      f32x4 au = {0.f,0.f,0.f,0.f};
      #pragma unroll
      for (int ks = 0; ks < 4; ++ks)
        au = __builtin_amdgcn_mfma_f32_16x16x32_f16(af[ks], bu[ks], au, 0, 0, 0);
      const int h = l15 >> 1, which = l15 & 1;
      float* vw = ws + (which ? OFF_VW2 : OFF_VW1) + ((size_t)(b*Hh + h)*Tt + t)*Nn;
      #pragma unroll
      for (int rg2 = 0; rg2 < 4; ++rg2)
        vw[rowb + rg2] = au[rg2];
    }
  }
}

// ---------------- kernel 3: attn — streaming (no chunk barriers), clamp-exp ----------------
// block = (b,h,quarter): 512 blocks x 512 thr. vw staged in LDS ONCE (1 barrier);
// K/Q loaded per-t directly from global (coalesced per lane, pipelined by unroll).
__global__ __launch_bounds__(512, 4) void k_attn(float* __restrict__ ws) {
  __shared__ float vw1_l[Tt][16], vw2_l[Tt][16];   // 8 KB
  const int tid = threadIdx.x;
  const int blk = blockIdx.x;         // bh*4 + quarter
  const int quarter = blk & 3;
  const int bh = blk >> 2;
  const int b = bh >> 3;
  const int i0 = quarter * 16;
  const int lane = tid & 63;          // j
  const int ig = tid >> 6;            // wave 0..7 -> i pair
  const int j = lane;
  const uint32_t* kh = (const uint32_t*)((const _Float16*)(ws + OFF_KH) + (size_t)bh*Tt*Nn*HD);
  const uint32_t* qh = (const uint32_t*)((const _Float16*)(ws + OFF_QH) + (size_t)bh*Tt*Nn*HD);
  const float* vw1 = ws + OFF_VW1 + (size_t)bh*Tt*Nn;
  const float* vw2 = ws + OFF_VW2 + (size_t)bh*Tt*Nn;
  float* e = ws + OFF_E + (size_t)b*Nn*Nn;
  float S0 = 0.f, S1 = 0.f, A10 = 0.f, A11 = 0.f, A20 = 0.f, A21 = 0.f;
  const float scale = 0.08838834764831845f; // 1/sqrt(128)

  // stage vw once: 2 x 64t x 16i = 2048 floats, 4/thread
  #pragma unroll
  for (int s = 0; s < 4; ++s) {
    int idx = tid + s*512;
    int which = idx >> 10, rem = idx & 1023;
    int t = rem >> 4, il = rem & 15;
    float v = (which ? vw2 : vw1)[(size_t)t*Nn + i0 + il];
    if (which) vw2_l[t][il] = v; else vw1_l[t][il] = v;
  }
  __syncthreads();

  #pragma unroll 4
  for (int tt = 0; tt < Tt; ++tt) {
    // K quarter slice: lane's 8B of the contiguous 512B row-block
    uint2 kp = *(const uint2*)&kh[((size_t)tt*Nn + i0)*8 + lane*2];
    // Q row j: 32B
    uint4 qa = *(const uint4*)&qh[((size_t)tt*Nn + j)*8];
    uint4 qb = *(const uint4*)&qh[((size_t)tt*Nn + j)*8 + 4];
    float2 v1 = *(const float2*)&vw1_l[tt][ig*2];
    float2 v2 = *(const float2*)&vw2_l[tt][ig*2];
    #pragma unroll
    for (int p = 0; p < 2; ++p) {
      const int base = (ig*2 + p)*4;
      float s = 0.f;
      s = fdot2(bcast_lane(kp.x, base+0), qa.x, s);
      s = fdot2(bcast_lane(kp.y, base+0), qa.y, s);
      s = fdot2(bcast_lane(kp.x, base+1), qa.z, s);
      s = fdot2(bcast_lane(kp.y, base+1), qa.w, s);
      s = fdot2(bcast_lane(kp.x, base+2), qb.x, s);
      s = fdot2(bcast_lane(kp.y, base+2), qb.y, s);
      s = fdot2(bcast_lane(kp.x, base+3), qb.z, s);
      s = fdot2(bcast_lane(kp.y, base+3), qb.w, s);
      s = fminf(fmaxf(s * scale, -60.f), 60.f);
      float ee = __expf(s);
      if (p == 0) {
        S0 += ee; A10 = fmaf(ee, v1.x, A10); A20 = fmaf(ee, v2.x, A20);
      } else {
        S1 += ee; A11 = fmaf(ee, v1.y, A11); A21 = fmaf(ee, v2.y, A21);
      }
    }
  }
  {
    const int i = i0 + ig*2;
    float inv0 = 1.f / S0, inv1 = 1.f / S1;
    atomicAdd(&e[i*Nn + j], A10 * inv0);
    atomicAdd(&e[j*Nn + i], A20 * inv0);
    atomicAdd(&e[(i+1)*Nn + j], A11 * inv1);
    atomicAdd(&e[j*Nn + i + 1], A21 * inv1);
  }
}

// ---------------- kernel 4: decode GRU step + vv ----------------
__global__ __launch_bounds__(384) void k_decode(
    const float* __restrict__ x, const float* __restrict__ W_hh,
    const float* __restrict__ b_hh, const float* __restrict__ W_val,
    const float* __restrict__ b_val, float* __restrict__ ws) {
  __shared__ float h_lds[4][Dd];
  __shared__ float g_lds[4][4*Dd];
  __shared__ float xt[4][Ss];
  const int tid = threadIdx.x;
  const int blk = blockIdx.x;
  const int row0 = blk * 4;
  const int b = row0 >> 6;
  const int n0 = row0 & 63;
  const float* ys = ws + OFF_YS;
  const float* Wx = ws + OFF_WX;
  const float* bxp = ws + OFF_BX;
  if (tid < Dd) {
    for (int r = 0; r < 4; ++r)
      h_lds[r][tid] = ys[(size_t)((Tt-1)*BN + row0 + r)*Dd + tid];
  }
  if (tid >= 320 && tid < 336) {
    int q = tid - 320; int r = q >> 2, s = q & 3;
    xt[r][s] = x[((size_t)(b*(Tt+1) + Tt)*Nn + (n0 + r))*Ss + s];
  }
  const int c = tid;
  const float bhh = b_hh[c];
  const float wx0 = Wx[0*G3 + c], wx1 = Wx[1*G3 + c], wx2 = Wx[2*G3 + c], wx3 = Wx[3*G3 + c];
  const float bxv = bxp[c];
  __syncthreads();
  float acc[4] = {bhh, bhh, bhh, bhh};
  for (int k = 0; k < Dd; k += 4) {
    float w0 = W_hh[(k+0)*G3 + c];
    float w1 = W_hh[(k+1)*G3 + c];
    float w2 = W_hh[(k+2)*G3 + c];
    float w3 = W_hh[(k+3)*G3 + c];
    #pragma unroll
    for (int r = 0; r < 4; ++r) {
      float4 hv = *(const float4*)&h_lds[r][k];
      acc[r] = fmaf(hv.x, w0, acc[r]);
      acc[r] = fmaf(hv.y, w1, acc[r]);
      acc[r] = fmaf(hv.z, w2, acc[r]);
      acc[r] = fmaf(hv.w, w3, acc[r]);
    }
  }
  float gi[4];
  #pragma unroll
  for (int r = 0; r < 4; ++r) {
    float g = bxv;
    g = fmaf(xt[r][0], wx0, g);
    g = fmaf(xt[r][1], wx1, g);
    g = fmaf(xt[r][2], wx2, g);
    g = fmaf(xt[r][3], wx3, g);
    gi[r] = g;
  }
  if (c < 2*Dd) {
    #pragma unroll
    for (int r = 0; r < 4; ++r) g_lds[r][c] = acc[r] + gi[r];
  } else {
    #pragma unroll
    for (int r = 0; r < 4; ++r) { g_lds[r][c] = gi[r]; g_lds[r][c + Dd] = acc[r]; }
  }
  __syncthreads();
  if (tid < Dd) {
    const int d = tid;
    #pragma unroll
    for (int r = 0; r < 4; ++r) {
      float rg = fast_sigmoid(g_lds[r][d]);
      float zg = fast_sigmoid(g_lds[r][Dd + d]);
      float ng = fast_tanh(fmaf(rg, g_lds[r][3*Dd + d], g_lds[r][2*Dd + d]));
      float hn = fmaf(zg, h_lds[r][d] - ng, ng);
      h_lds[r][d] = hn;
    }
  }
  __syncthreads();
  if (tid < Dd) {
    const int c2 = tid;
    for (int r = 0; r < 4; ++r) {
      float a = b_val[c2];
      for (int k = 0; k < Dd; k += 4) {
        float4 hv = *(const float4*)&h_lds[r][k];
        a = fmaf(hv.x, W_val[(k+0)*Dd + c2], a);
        a = fmaf(hv.y, W_val[(k+1)*Dd + c2], a);
        a = fmaf(hv.z, W_val[(k+2)*Dd + c2], a);
        a = fmaf(hv.w, W_val[(k+3)*Dd + c2], a);
      }
      ws[OFF_VV + (size_t)(row0 + r)*Dd + c2] = a;
    }
  }
}

// ---------------- kernel 5: weight/p/dec/mu/sig — all via MFMA ----------------
__global__ __launch_bounds__(256) void k_final(
    const float* __restrict__ b_dec, const float* __restrict__ b_mu,
    const float* __restrict__ b_sig, const float* __restrict__ b_att,
    float* __restrict__ ws, float* __restrict__ out) {
  __shared__ __align__(16) _Float16 vvT[Dd][72];
  __shared__ __align__(16) _Float16 wl[16][72];
  __shared__ __align__(16) _Float16 A2[16][264];
  __shared__ __align__(16) _Float16 A3[16][136];
  const int tid = threadIdx.x;
  const int wave = tid >> 6, lane = tid & 63;
  const int l15 = lane & 15, lk = lane >> 4;
  const int blk = blockIdx.x;
  const int b = blk >> 2, iq = blk & 3, i0 = iq*16;
  const float* vv = ws + OFF_VV + (size_t)b*64*Dd;
  const float* e  = ws + OFF_E + (size_t)b*Nn*Nn;
  const float batt = b_att[0];

  for (int idx = tid; idx < 64*Dd/4; idx += 256) {
    int r = idx >> 5, k4 = (idx & 31)*4;
    float4 v = *(const float4*)&vv[r*Dd + k4];
    vvT[k4+0][r] = (_Float16)v.x;
    vvT[k4+1][r] = (_Float16)v.y;
    vvT[k4+2][r] = (_Float16)v.z;
    vvT[k4+3][r] = (_Float16)v.w;
    int rl = r - i0;
    if (rl >= 0 && rl < 16) {
      A2[rl][k4+0] = (_Float16)v.x;
      A2[rl][k4+1] = (_Float16)v.y;
      A2[rl][k4+2] = (_Float16)v.z;
      A2[rl][k4+3] = (_Float16)v.w;
    }
  }
  for (int idx = tid; idx < 16*64; idx += 256) {
    int il = idx >> 6, jj = idx & 63;
    int i = i0 + il;
    float v = (i == jj) ? 0.f : fast_tanh(e[i*Nn + jj] + batt + 0.5f);
    wl[il][jj] = (_Float16)v;
  }
  __syncthreads();

  {
    f16x8 a0 = *(const f16x8*)&wl[l15][lk*8];
    f16x8 a1 = *(const f16x8*)&wl[l15][32 + lk*8];
    #pragma unroll
    for (int q = 0; q < 2; ++q) {
      const int nt = wave*2 + q;
      f16x8 b0 = *(const f16x8*)&vvT[nt*16 + l15][lk*8];
      f16x8 b1 = *(const f16x8*)&vvT[nt*16 + l15][32 + lk*8];
      f32x4 acc = {0.f,0.f,0.f,0.f};
      acc = __builtin_amdgcn_mfma_f32_16x16x32_f16(a0, b0, acc, 0, 0, 0);
      acc = __builtin_amdgcn_mfma_f32_16x16x32_f16(a1, b1, acc, 0, 0, 0);
      #pragma unroll
      for (int r = 0; r < 4; ++r)
        A2[lk*4 + r][128 + nt*16 + l15] = (_Float16)(acc[r] * (1.f/64.f));
    }
  }
  __syncthreads();

  const f16x8* WDF = (const f16x8*)(ws + OFF_WDF);
  {
    f16x8 ad[8];
    #pragma unroll
    for (int ks = 0; ks < 8; ++ks)
      ad[ks] = *(const f16x8*)&A2[l15][ks*32 + lk*8];
    #pragma unroll
    for (int q = 0; q < 2; ++q) {
      const int nt = wave*2 + q;
      const float bias = b_dec[nt*16 + l15];
      f32x4 acc = {bias, bias, bias, bias};
      #pragma unroll
      for (int ks = 0; ks < 8; ++ks)
        acc = __builtin_amdgcn_mfma_f32_16x16x32_f16(
            ad[ks], WDF[(size_t)((nt*8 + ks)*64) + lane], acc, 0, 0, 0);
      #pragma unroll
      for (int r = 0; r < 4; ++r)
        A3[lk*4 + r][nt*16 + l15] = (_Float16)acc[r];
    }
  }
  __syncthreads();

  if (wave == 0) {
    const f16x8* WMF = (const f16x8*)(ws + OFF_WMF);
    f16x8 ah[4];
    #pragma unroll
    for (int ks = 0; ks < 4; ++ks)
      ah[ks] = *(const f16x8*)&A3[l15][ks*32 + lk*8];
    const float bias = (l15 < 4) ? b_mu[l15] : ((l15 < 8) ? b_sig[l15 - 4] : 0.f);
    f32x4 acc = {bias, bias, bias, bias};
    #pragma unroll
    for (int ks = 0; ks < 4; ++ks)
      acc = __builtin_amdgcn_mfma_f32_16x16x32_f16(
          ah[ks], WMF[(size_t)(ks*64) + lane], acc, 0, 0, 0);
    if (l15 < 8) {
      const int which = l15 >> 2, s = l15 & 3;
      #pragma unroll
      for (int r = 0; r < 4; ++r) {
        float v = acc[r];
        if (which) v = 1.f/(1.f + __expf(-v)) + 1e-6f;
        out[(size_t)which*(Bb*Nn*Ss) + (size_t)(b*64 + i0 + lk*4 + r)*Ss + s] = v;
      }
    }
  }
}

extern "C" void kernel_launch(void* const* d_in, const int* in_sizes, int n_in,
                              void* d_out, int out_size, void* d_ws, size_t ws_size,
                              hipStream_t stream) {
  const float* x     = (const float*)d_in[0];
  const float* W_se  = (const float*)d_in[1];
  const float* b_se  = (const float*)d_in[2];
  const float* W_init= (const float*)d_in[3];
  const float* b_init= (const float*)d_in[4];
  const float* W_ih  = (const float*)d_in[5];
  const float* W_hh  = (const float*)d_in[6];
  const float* b_ih  = (const float*)d_in[7];
  const float* b_hh  = (const float*)d_in[8];
  const float* W_kc  = (const float*)d_in[9];
  const float* W_qc  = (const float*)d_in[10];
  const float* W_vc  = (const float*)d_in[11];
  const float* W_att = (const float*)d_in[12];
  const float* b_att = (const float*)d_in[13];
  const float* W_val = (const float*)d_in[14];
  const float* b_val = (const float*)d_in[15];
  const float* W_dec = (const float*)d_in[16];
  const float* b_dec = (const float*)d_in[17];
  const float* W_mu  = (const float*)d_in[18];
  const float* b_mu  = (const float*)d_in[19];
  const float* W_sig = (const float*)d_in[20];
  const float* b_sig = (const float*)d_in[21];
  float* ws = (float*)d_ws;
  float* out = (float*)d_out;

  if (ws_size < (size_t)WS_FLOATS * sizeof(float)) return;

  hipMemsetAsync(ws + OFF_E, 0, (size_t)Bb*Nn*Nn*sizeof(float), stream);
  k_precompute<<<51, 384, 0, stream>>>(W_se, b_se, W_ih, b_ih, W_hh, W_kc, W_qc,
                                       W_vc, W_att, W_dec, W_mu, W_sig, ws);
  k_gru<<<BN/4, 512, 0, stream>>>(x, W_init, b_init, b_hh, ws);
  k_kqv<<<Bb*Tt, 256, 0, stream>>>(ws);
  k_attn<<<Bb*Hh*4, 512, 0, stream>>>(ws);
  k_decode<<<BN/4, 384, 0, stream>>>(x, W_hh, b_hh, W_val, b_val, ws);
  k_final<<<Bb*4, 256, 0, stream>>>(b_dec, b_mu, b_sig, b_att, ws, out);
}

// Round 16
// 139.086 us; speedup vs baseline: 1.6060x; 1.1648x over previous
//
#include <hip/hip_runtime.h>
#include <math.h>

#define Bb 16
#define Tt 64
#define Nn 64
#define Ss 4
#define Dd 128
#define Hh 8
#define HD 16
#define BN 1024
#define G3 384   // 3*D

// workspace layout (in floats)
#define OFF_WX   0                              // 4*384
#define OFF_BX   1536                           // 384
#define OFF_YS   4096                           // T*BN*D
#define OFF_KH   (OFF_YS + Tt*BN*Dd)            // f16 [b,h][t][n][16]
#define OFF_QH   (OFF_KH + Bb*Hh*Tt*Nn*HD/2)
#define OFF_VW1  (OFF_QH + Bb*Hh*Tt*Nn*HD/2)    // f32 [b,h][t][n]
#define OFF_VW2  (OFF_VW1 + Bb*Hh*Tt*Nn)
#define OFF_E    (OFF_VW2 + Bb*Hh*Tt*Nn)        // B*N*N
#define OFF_VV   (OFF_E + Bb*Nn*Nn)             // BN*D
#define OFF_WKQ  (OFF_VV + BN*Dd)               // f16 frag [W_kc|W_qc|u]: 17408 floats
#define OFF_WT   (OFF_WKQ + 17408)              // f16 frag W_hh: 24576 floats
#define OFF_WDF  (OFF_WT + 24576)               // f16 frag W_dec: 16384 floats
#define OFF_WMF  (OFF_WDF + 16384)              // f16 frag [W_mu|W_sig]: 1024 floats
#define WS_FLOATS (OFF_WMF + 1024)

typedef _Float16 half2_t __attribute__((ext_vector_type(2)));
typedef _Float16 f16x8 __attribute__((ext_vector_type(8)));
typedef float f32x4 __attribute__((ext_vector_type(4)));

__device__ __forceinline__ float fast_sigmoid(float v) {
  return 1.f / (1.f + __expf(-v));
}
__device__ __forceinline__ float fast_tanh(float v) {
  float e2 = __expf(2.f * v);
  return 1.f - 2.f / (e2 + 1.f);
}

// ---------------- kernel 0: fold weights + pack all MFMA B-fragments ----------------
__global__ __launch_bounds__(384) void k_precompute(
    const float* __restrict__ W_se, const float* __restrict__ b_se,
    const float* __restrict__ W_ih, const float* __restrict__ b_ih,
    const float* __restrict__ W_hh,
    const float* __restrict__ W_kc, const float* __restrict__ W_qc,
    const float* __restrict__ W_vc, const float* __restrict__ W_att,
    const float* __restrict__ W_dec, const float* __restrict__ W_mu,
    const float* __restrict__ W_sig,
    float* __restrict__ ws) {
  const int tid = threadIdx.x;
  if (blockIdx.x == 50) {
    _Float16* WF = (_Float16*)(ws + OFF_WMF);
    for (int idx = tid; idx < 4*64*8; idx += 384) {
      int ks = idx >> 9, l = (idx >> 3) & 63, j = idx & 7;
      int k = ks*32 + (l >> 4)*8 + j;
      int c16 = l & 15;
      float v = (c16 < 4) ? W_mu[(size_t)k*Ss + c16]
              : ((c16 < 8) ? W_sig[(size_t)k*Ss + c16 - 4] : 0.f);
      WF[(size_t)(ks*64 + l)*8 + j] = (_Float16)v;
    }
    return;
  }
  if (blockIdx.x >= 42) {
    const int nt = blockIdx.x - 42;  // 0..7
    _Float16* WF = (_Float16*)(ws + OFF_WDF);
    for (int idx = tid; idx < 8*64*8; idx += 384) {
      int ks = idx >> 9, l = (idx >> 3) & 63, j = idx & 7;
      int k = ks*32 + (l >> 4)*8 + j;
      int c = nt*16 + (l & 15);
      WF[(size_t)((nt*8 + ks)*64 + l)*8 + j] = (_Float16)W_dec[(size_t)k*Dd + c];
    }
    return;
  }
  if (blockIdx.x >= 25) {
    const int nt = blockIdx.x - 25;  // 0..16
    _Float16* WF = (_Float16*)(ws + OFF_WKQ);
    for (int idx = tid; idx < 4*64*8; idx += 384) {
      int ks = idx >> 9, l = (idx >> 3) & 63, j = idx & 7;
      int k = ks*32 + (l >> 4)*8 + j;
      int c16 = l & 15;
      float v;
      if (nt < 16) {
        int cg = nt*16 + c16;
        v = (cg < Dd) ? W_kc[(size_t)k*Dd + cg] : W_qc[(size_t)k*Dd + cg - Dd];
      } else {
        int h = c16 >> 1, which = c16 & 1;
        float s = 0.f;
        for (int d = 0; d < HD; ++d)
          s = fmaf(W_vc[(size_t)k*Dd + h*HD + d], W_att[which*Dd + h*HD + d], s);
        v = s;
      }
      WF[(size_t)((nt*4 + ks)*64 + l)*8 + j] = (_Float16)v;
    }
    return;
  }
  if (blockIdx.x > 0) {
    const int nt = blockIdx.x - 1;  // 0..23
    _Float16* WF = (_Float16*)(ws + OFF_WT);
    for (int idx = tid; idx < 4*64*8; idx += 384) {
      int ks = idx >> 9, l = (idx >> 3) & 63, j = idx & 7;
      int k = ks*32 + (l >> 4)*8 + j;
      int c = nt*16 + (l & 15);
      WF[(size_t)((nt*4 + ks)*64 + l)*8 + j] = (_Float16)W_hh[(size_t)k*G3 + c];
    }
    return;
  }
  const int c = tid;
  float* Wx = ws + OFF_WX; float* bx = ws + OFF_BX;
  float accb = b_ih[c];
  float a0 = 0.f, a1 = 0.f, a2 = 0.f, a3 = 0.f;
  for (int k = 0; k < Dd; ++k) {
    float w = W_ih[k*G3 + c];
    accb = fmaf(b_se[k], w, accb);
    a0 = fmaf(W_se[0*Dd + k], w, a0);
    a1 = fmaf(W_se[1*Dd + k], w, a1);
    a2 = fmaf(W_se[2*Dd + k], w, a2);
    a3 = fmaf(W_se[3*Dd + k], w, a3);
  }
  bx[c] = accb;
  Wx[0*G3 + c] = a0; Wx[1*G3 + c] = a1; Wx[2*G3 + c] = a2; Wx[3*G3 + c] = a3;
}

// ---------------- kernel 1: GRU via MFMA (f16), W fragments register-resident ----------------
__global__ __launch_bounds__(512, 2) void k_gru(
    const float* __restrict__ x, const float* __restrict__ W_init,
    const float* __restrict__ b_init,
    const float* __restrict__ b_hh, float* __restrict__ ws) {
  __shared__ __align__(16) _Float16 h_l[4][Dd + 8];
  __shared__ float gg[4][G3];
  __shared__ float xt_l[Tt+1][4][Ss];
  const int tid = threadIdx.x;
  const int wave = tid >> 6;
  const int lane = tid & 63;
  const int l15 = lane & 15;
  const int lk = lane >> 4;
  const int blk = blockIdx.x;
  const int row0 = blk * 4;
  const int b = row0 >> 6;
  const int n0 = row0 & 63;
  float* ys = ws + OFF_YS;
  const float* Wx = ws + OFF_WX;
  const float* bxp = ws + OFF_BX;

  const f16x8* WF = (const f16x8*)(ws + OFF_WT);
  f16x8 wf[3][4];
  #pragma unroll
  for (int i = 0; i < 3; ++i)
    #pragma unroll
    for (int ks = 0; ks < 4; ++ks)
      wf[i][ks] = WF[(size_t)((wave*3 + i)*4 + ks)*64 + lane];
  float br[3];
  #pragma unroll
  for (int i = 0; i < 3; ++i) br[i] = b_hh[(wave*3 + i)*16 + l15];

  const int row = tid >> 7, d = tid & 127;
  float wxr[3][4], bx3[3];
  #pragma unroll
  for (int g = 0; g < 3; ++g) {
    bx3[g] = bxp[g*Dd + d];
    #pragma unroll
    for (int s = 0; s < 4; ++s) wxr[g][s] = Wx[s*G3 + g*Dd + d];
  }

  for (int idx = tid; idx < (Tt+1)*4*Ss; idx += 512) {
    int t = idx >> 4, r = (idx >> 2) & 3, s = idx & 3;
    xt_l[t][r][s] = x[((size_t)(b*(Tt+1) + t)*Nn + (n0 + r))*Ss + s];
  }
  __syncthreads();

  float hprev;
  {
    float h0 = b_init[d];
    #pragma unroll
    for (int s = 0; s < Ss; ++s)
      h0 = fmaf(xt_l[0][row][s], W_init[s*Dd + d], h0);
    hprev = h0;
    h_l[row][d] = (_Float16)h0;
  }
  __syncthreads();

  for (int t = 0; t < Tt; ++t) {
    f16x8 af[4];
    #pragma unroll
    for (int ks = 0; ks < 4; ++ks)
      af[ks] = *(const f16x8*)&h_l[l15 & 3][ks*32 + lk*8];
    #pragma unroll
    for (int i = 0; i < 3; ++i) {
      f32x4 acc = {br[i], br[i], br[i], br[i]};
      #pragma unroll
      for (int ks = 0; ks < 4; ++ks)
        acc = __builtin_amdgcn_mfma_f32_16x16x32_f16(af[ks], wf[i][ks], acc, 0, 0, 0);
      if (lane < 16) {
        const int col = (wave*3 + i)*16 + l15;
        gg[0][col] = acc[0];
        gg[1][col] = acc[1];
        gg[2][col] = acc[2];
        gg[3][col] = acc[3];
      }
    }
    __syncthreads();
    {
      float gi_r = bx3[0], gi_z = bx3[1], gi_n = bx3[2];
      #pragma unroll
      for (int s = 0; s < 4; ++s) {
        float xv = xt_l[t][row][s];
        gi_r = fmaf(xv, wxr[0][s], gi_r);
        gi_z = fmaf(xv, wxr[1][s], gi_z);
        gi_n = fmaf(xv, wxr[2][s], gi_n);
      }
      float rg = fast_sigmoid(gi_r + gg[row][d]);
      float zg = fast_sigmoid(gi_z + gg[row][Dd + d]);
      float ng = fast_tanh(fmaf(rg, gg[row][2*Dd + d], gi_n));
      float hnew = fmaf(zg, hprev - ng, ng);
      hprev = hnew;
      h_l[row][d] = (_Float16)hnew;
      ys[(size_t)(t*BN + row0 + row)*Dd + d] = hnew;
    }
    __syncthreads();
  }
}

// ---------------- kernel 2: k,q,vw via MFMA (f16); K/Q written f16 head-major ----------------
__global__ __launch_bounds__(256, 2) void k_kqv(float* __restrict__ ws) {
  __shared__ __align__(16) _Float16 ysl[64][136];
  const int tid = threadIdx.x;
  const int blk = blockIdx.x;    // b*T + t
  const int b = blk >> 6, t = blk & 63;
  const int wave = tid >> 6, lane = tid & 63;
  const int l15 = lane & 15, lk = lane >> 4;

  const f16x8* WKQ = (const f16x8*)(ws + OFF_WKQ);
  f16x8 bf0[4], bf1[4], bf2[4], bf3[4], bu[4];
  #pragma unroll
  for (int ks = 0; ks < 4; ++ks) {
    bf0[ks] = WKQ[(size_t)((wave*4 + 0)*4 + ks)*64 + lane];
    bf1[ks] = WKQ[(size_t)((wave*4 + 1)*4 + ks)*64 + lane];
    bf2[ks] = WKQ[(size_t)((wave*4 + 2)*4 + ks)*64 + lane];
    bf3[ks] = WKQ[(size_t)((wave*4 + 3)*4 + ks)*64 + lane];
    bu[ks]  = WKQ[(size_t)(16*4 + ks)*64 + lane];
  }

  const float* ysrc = ws + OFF_YS + ((size_t)t*BN + b*64)*Dd;
  for (int idx = tid; idx < 64*16; idx += 256) {
    int r = idx >> 4, k8 = (idx & 15) * 8;
    float4 v0 = *(const float4*)&ysrc[r*Dd + k8];
    float4 v1 = *(const float4*)&ysrc[r*Dd + k8 + 4];
    f16x8 hv;
    hv[0] = (_Float16)v0.x; hv[1] = (_Float16)v0.y;
    hv[2] = (_Float16)v0.z; hv[3] = (_Float16)v0.w;
    hv[4] = (_Float16)v1.x; hv[5] = (_Float16)v1.y;
    hv[6] = (_Float16)v1.z; hv[7] = (_Float16)v1.w;
    *(f16x8*)&ysl[r][k8] = hv;
  }
  __syncthreads();

  _Float16* khd = (_Float16*)(ws + OFF_KH);
  _Float16* qhd = (_Float16*)(ws + OFF_QH);

  #pragma unroll
  for (int mt = 0; mt < 4; ++mt) {
    f16x8 af[4];
    #pragma unroll
    for (int ks = 0; ks < 4; ++ks)
      af[ks] = *(const f16x8*)&ysl[mt*16 + l15][ks*32 + lk*8];
    f32x4 a0 = {0.f,0.f,0.f,0.f}, a1 = a0, a2 = a0, a3 = a0;
    #pragma unroll
    for (int ks = 0; ks < 4; ++ks) {
      a0 = __builtin_amdgcn_mfma_f32_16x16x32_f16(af[ks], bf0[ks], a0, 0, 0, 0);
      a1 = __builtin_amdgcn_mfma_f32_16x16x32_f16(af[ks], bf1[ks], a1, 0, 0, 0);
      a2 = __builtin_amdgcn_mfma_f32_16x16x32_f16(af[ks], bf2[ks], a2, 0, 0, 0);
      a3 = __builtin_amdgcn_mfma_f32_16x16x32_f16(af[ks], bf3[ks], a3, 0, 0, 0);
    }
    const int rowb = mt*16 + lk*4;
    #pragma unroll
    for (int nti = 0; nti < 4; ++nti) {
      f32x4 av = (nti == 0) ? a0 : (nti == 1) ? a1 : (nti == 2) ? a2 : a3;
      const int gc = wave*64 + nti*16 + l15;
      const int hh = (gc >> 4) & 7;
      const int dd2 = gc & 15;
      _Float16* base = (gc < Dd) ? khd : qhd;
      const size_t rowbase = ((size_t)(b*Hh + hh)*Tt + t)*Nn*HD;
      #pragma unroll
      for (int rg2 = 0; rg2 < 4; ++rg2)
        base[rowbase + (size_t)(rowb + rg2)*HD + dd2] = (_Float16)av[rg2];
    }
    if (wave == 3) {
      f32x4 au = {0.f,0.f,0.f,0.f};
      #pragma unroll
      for (int ks = 0; ks < 4; ++ks)
        au = __builtin_amdgcn_mfma_f32_16x16x32_f16(af[ks], bu[ks], au, 0, 0, 0);
      const int h = l15 >> 1, which = l15 & 1;
      float* vw = ws + (which ? OFF_VW2 : OFF_VW1) + ((size_t)(b*Hh + h)*Tt + t)*Nn;
      #pragma unroll
      for (int rg2 = 0; rg2 < 4; ++rg2)
        vw[rowb + rg2] = au[rg2];
    }
  }
}

// ---------------- kernel 3: attn — QK^T via MFMA (zero-padded K=16), clamp-exp ----------------
// block = (b,h): 128 blocks x 1024 thr (16 waves = 4x4 (i-tile,j-tile)).
// Wave owns a 16x16 (i,j) tile; per t: A-frag=K-tile, B-frag=Q-tile (upper 16 k
// zero), 1 MFMA -> 4 scores/lane at (i=i0+lk*4+r, j=j0+l15); vw as float4 LDS.
__global__ __launch_bounds__(1024) void k_attn(float* __restrict__ ws) {
  __shared__ float vw1_l[Tt][Nn];   // 16 KB
  __shared__ float vw2_l[Tt][Nn];   // 16 KB
  const int tid = threadIdx.x;
  const int bh = blockIdx.x;
  const int b = bh >> 3;
  const int wave = tid >> 6;
  const int it = wave >> 2, jt = wave & 3;
  const int i0 = it*16, j0 = jt*16;
  const int lane = tid & 63;
  const int l15 = lane & 15, lk = lane >> 4;
  const _Float16* kh = (const _Float16*)(ws + OFF_KH) + (size_t)bh*Tt*Nn*HD;
  const _Float16* qh = (const _Float16*)(ws + OFF_QH) + (size_t)bh*Tt*Nn*HD;
  const float* vw1 = ws + OFF_VW1 + (size_t)bh*Tt*Nn;
  const float* vw2 = ws + OFF_VW2 + (size_t)bh*Tt*Nn;
  float* e = ws + OFF_E + (size_t)b*Nn*Nn;
  const float scale = 0.08838834764831845f; // 1/sqrt(128)

  // stage vw full [64t][64i]: 2*4096 floats, 4 per thread
  #pragma unroll
  for (int s = 0; s < 4; ++s) {
    int idx = tid + s*1024;
    ((float*)vw1_l)[idx] = vw1[idx];
    ((float*)vw2_l)[idx] = vw2[idx];
  }
  __syncthreads();

  float S[4] = {0.f,0.f,0.f,0.f};
  float A1[4] = {0.f,0.f,0.f,0.f};
  float A2[4] = {0.f,0.f,0.f,0.f};
  const bool realk = (lk < 2);   // lanes lk>=2 feed zeros (K padded 16->32)

  #pragma unroll 4
  for (int t = 0; t < Tt; ++t) {
    f16x8 af = {0,0,0,0,0,0,0,0}, bf = {0,0,0,0,0,0,0,0};
    if (realk) {
      af = *(const f16x8*)&kh[((size_t)t*Nn + i0 + l15)*HD + lk*8];
      bf = *(const f16x8*)&qh[((size_t)t*Nn + j0 + l15)*HD + lk*8];
    }
    f32x4 sc = {0.f,0.f,0.f,0.f};
    sc = __builtin_amdgcn_mfma_f32_16x16x32_f16(af, bf, sc, 0, 0, 0);
    float4 w1 = *(const float4*)&vw1_l[t][i0 + lk*4];
    float4 w2 = *(const float4*)&vw2_l[t][i0 + lk*4];
    const float* w1p = (const float*)&w1;
    const float* w2p = (const float*)&w2;
    #pragma unroll
    for (int r = 0; r < 4; ++r) {
      float s = fminf(fmaxf(sc[r] * scale, -60.f), 60.f);
      float ee = __expf(s);
      S[r] += ee;
      A1[r] = fmaf(ee, w1p[r], A1[r]);
      A2[r] = fmaf(ee, w2p[r], A2[r]);
    }
  }
  {
    const int j = j0 + l15;
    #pragma unroll
    for (int r = 0; r < 4; ++r) {
      const int i = i0 + lk*4 + r;
      float inv = 1.f / S[r];
      atomicAdd(&e[i*Nn + j], A1[r] * inv);
      atomicAdd(&e[j*Nn + i], A2[r] * inv);
    }
  }
}

// ---------------- kernel 4: decode GRU step + vv ----------------
__global__ __launch_bounds__(384) void k_decode(
    const float* __restrict__ x, const float* __restrict__ W_hh,
    const float* __restrict__ b_hh, const float* __restrict__ W_val,
    const float* __restrict__ b_val, float* __restrict__ ws) {
  __shared__ float h_lds[4][Dd];
  __shared__ float g_lds[4][4*Dd];
  __shared__ float xt[4][Ss];
  const int tid = threadIdx.x;
  const int blk = blockIdx.x;
  const int row0 = blk * 4;
  const int b = row0 >> 6;
  const int n0 = row0 & 63;
  const float* ys = ws + OFF_YS;
  const float* Wx = ws + OFF_WX;
  const float* bxp = ws + OFF_BX;
  if (tid < Dd) {
    for (int r = 0; r < 4; ++r)
      h_lds[r][tid] = ys[(size_t)((Tt-1)*BN + row0 + r)*Dd + tid];
  }
  if (tid >= 320 && tid < 336) {
    int q = tid - 320; int r = q >> 2, s = q & 3;
    xt[r][s] = x[((size_t)(b*(Tt+1) + Tt)*Nn + (n0 + r))*Ss + s];
  }
  const int c = tid;
  const float bhh = b_hh[c];
  const float wx0 = Wx[0*G3 + c], wx1 = Wx[1*G3 + c], wx2 = Wx[2*G3 + c], wx3 = Wx[3*G3 + c];
  const float bxv = bxp[c];
  __syncthreads();
  float acc[4] = {bhh, bhh, bhh, bhh};
  for (int k = 0; k < Dd; k += 4) {
    float w0 = W_hh[(k+0)*G3 + c];
    float w1 = W_hh[(k+1)*G3 + c];
    float w2 = W_hh[(k+2)*G3 + c];
    float w3 = W_hh[(k+3)*G3 + c];
    #pragma unroll
    for (int r = 0; r < 4; ++r) {
      float4 hv = *(const float4*)&h_lds[r][k];
      acc[r] = fmaf(hv.x, w0, acc[r]);
      acc[r] = fmaf(hv.y, w1, acc[r]);
      acc[r] = fmaf(hv.z, w2, acc[r]);
      acc[r] = fmaf(hv.w, w3, acc[r]);
    }
  }
  float gi[4];
  #pragma unroll
  for (int r = 0; r < 4; ++r) {
    float g = bxv;
    g = fmaf(xt[r][0], wx0, g);
    g = fmaf(xt[r][1], wx1, g);
    g = fmaf(xt[r][2], wx2, g);
    g = fmaf(xt[r][3], wx3, g);
    gi[r] = g;
  }
  if (c < 2*Dd) {
    #pragma unroll
    for (int r = 0; r < 4; ++r) g_lds[r][c] = acc[r] + gi[r];
  } else {
    #pragma unroll
    for (int r = 0; r < 4; ++r) { g_lds[r][c] = gi[r]; g_lds[r][c + Dd] = acc[r]; }
  }
  __syncthreads();
  if (tid < Dd) {
    const int d = tid;
    #pragma unroll
    for (int r = 0; r < 4; ++r) {
      float rg = fast_sigmoid(g_lds[r][d]);
      float zg = fast_sigmoid(g_lds[r][Dd + d]);
      float ng = fast_tanh(fmaf(rg, g_lds[r][3*Dd + d], g_lds[r][2*Dd + d]));
      float hn = fmaf(zg, h_lds[r][d] - ng, ng);
      h_lds[r][d] = hn;
    }
  }
  __syncthreads();
  if (tid < Dd) {
    const int c2 = tid;
    for (int r = 0; r < 4; ++r) {
      float a = b_val[c2];
      for (int k = 0; k < Dd; k += 4) {
        float4 hv = *(const float4*)&h_lds[r][k];
        a = fmaf(hv.x, W_val[(k+0)*Dd + c2], a);
        a = fmaf(hv.y, W_val[(k+1)*Dd + c2], a);
        a = fmaf(hv.z, W_val[(k+2)*Dd + c2], a);
        a = fmaf(hv.w, W_val[(k+3)*Dd + c2], a);
      }
      ws[OFF_VV + (size_t)(row0 + r)*Dd + c2] = a;
    }
  }
}

// ---------------- kernel 5: weight/p/dec/mu/sig — all via MFMA ----------------
__global__ __launch_bounds__(256) void k_final(
    const float* __restrict__ b_dec, const float* __restrict__ b_mu,
    const float* __restrict__ b_sig, const float* __restrict__ b_att,
    float* __restrict__ ws, float* __restrict__ out) {
  __shared__ __align__(16) _Float16 vvT[Dd][72];
  __shared__ __align__(16) _Float16 wl[16][72];
  __shared__ __align__(16) _Float16 A2[16][264];
  __shared__ __align__(16) _Float16 A3[16][136];
  const int tid = threadIdx.x;
  const int wave = tid >> 6, lane = tid & 63;
  const int l15 = lane & 15, lk = lane >> 4;
  const int blk = blockIdx.x;
  const int b = blk >> 2, iq = blk & 3, i0 = iq*16;
  const float* vv = ws + OFF_VV + (size_t)b*64*Dd;
  const float* e  = ws + OFF_E + (size_t)b*Nn*Nn;
  const float batt = b_att[0];

  for (int idx = tid; idx < 64*Dd/4; idx += 256) {
    int r = idx >> 5, k4 = (idx & 31)*4;
    float4 v = *(const float4*)&vv[r*Dd + k4];
    vvT[k4+0][r] = (_Float16)v.x;
    vvT[k4+1][r] = (_Float16)v.y;
    vvT[k4+2][r] = (_Float16)v.z;
    vvT[k4+3][r] = (_Float16)v.w;
    int rl = r - i0;
    if (rl >= 0 && rl < 16) {
      A2[rl][k4+0] = (_Float16)v.x;
      A2[rl][k4+1] = (_Float16)v.y;
      A2[rl][k4+2] = (_Float16)v.z;
      A2[rl][k4+3] = (_Float16)v.w;
    }
  }
  for (int idx = tid; idx < 16*64; idx += 256) {
    int il = idx >> 6, jj = idx & 63;
    int i = i0 + il;
    float v = (i == jj) ? 0.f : fast_tanh(e[i*Nn + jj] + batt + 0.5f);
    wl[il][jj] = (_Float16)v;
  }
  __syncthreads();

  {
    f16x8 a0 = *(const f16x8*)&wl[l15][lk*8];
    f16x8 a1 = *(const f16x8*)&wl[l15][32 + lk*8];
    #pragma unroll
    for (int q = 0; q < 2; ++q) {
      const int nt = wave*2 + q;
      f16x8 b0 = *(const f16x8*)&vvT[nt*16 + l15][lk*8];
      f16x8 b1 = *(const f16x8*)&vvT[nt*16 + l15][32 + lk*8];
      f32x4 acc = {0.f,0.f,0.f,0.f};
      acc = __builtin_amdgcn_mfma_f32_16x16x32_f16(a0, b0, acc, 0, 0, 0);
      acc = __builtin_amdgcn_mfma_f32_16x16x32_f16(a1, b1, acc, 0, 0, 0);
      #pragma unroll
      for (int r = 0; r < 4; ++r)
        A2[lk*4 + r][128 + nt*16 + l15] = (_Float16)(acc[r] * (1.f/64.f));
    }
  }
  __syncthreads();

  const f16x8* WDF = (const f16x8*)(ws + OFF_WDF);
  {
    f16x8 ad[8];
    #pragma unroll
    for (int ks = 0; ks < 8; ++ks)
      ad[ks] = *(const f16x8*)&A2[l15][ks*32 + lk*8];
    #pragma unroll
    for (int q = 0; q < 2; ++q) {
      const int nt = wave*2 + q;
      const float bias = b_dec[nt*16 + l15];
      f32x4 acc = {bias, bias, bias, bias};
      #pragma unroll
      for (int ks = 0; ks < 8; ++ks)
        acc = __builtin_amdgcn_mfma_f32_16x16x32_f16(
            ad[ks], WDF[(size_t)((nt*8 + ks)*64) + lane], acc, 0, 0, 0);
      #pragma unroll
      for (int r = 0; r < 4; ++r)
        A3[lk*4 + r][nt*16 + l15] = (_Float16)acc[r];
    }
  }
  __syncthreads();

  if (wave == 0) {
    const f16x8* WMF = (const f16x8*)(ws + OFF_WMF);
    f16x8 ah[4];
    #pragma unroll
    for (int ks = 0; ks < 4; ++ks)
      ah[ks] = *(const f16x8*)&A3[l15][ks*32 + lk*8];
    const float bias = (l15 < 4) ? b_mu[l15] : ((l15 < 8) ? b_sig[l15 - 4] : 0.f);
    f32x4 acc = {bias, bias, bias, bias};
    #pragma unroll
    for (int ks = 0; ks < 4; ++ks)
      acc = __builtin_amdgcn_mfma_f32_16x16x32_f16(
          ah[ks], WMF[(size_t)(ks*64) + lane], acc, 0, 0, 0);
    if (l15 < 8) {
      const int which = l15 >> 2, s = l15 & 3;
      #pragma unroll
      for (int r = 0; r < 4; ++r) {
        float v = acc[r];
        if (which) v = 1.f/(1.f + __expf(-v)) + 1e-6f;
        out[(size_t)which*(Bb*Nn*Ss) + (size_t)(b*64 + i0 + lk*4 + r)*Ss + s] = v;
      }
    }
  }
}

extern "C" void kernel_launch(void* const* d_in, const int* in_sizes, int n_in,
                              void* d_out, int out_size, void* d_ws, size_t ws_size,
                              hipStream_t stream) {
  const float* x     = (const float*)d_in[0];
  const float* W_se  = (const float*)d_in[1];
  const float* b_se  = (const float*)d_in[2];
  const float* W_init= (const float*)d_in[3];
  const float* b_init= (const float*)d_in[4];
  const float* W_ih  = (const float*)d_in[5];
  const float* W_hh  = (const float*)d_in[6];
  const float* b_ih  = (const float*)d_in[7];
  const float* b_hh  = (const float*)d_in[8];
  const float* W_kc  = (const float*)d_in[9];
  const float* W_qc  = (const float*)d_in[10];
  const float* W_vc  = (const float*)d_in[11];
  const float* W_att = (const float*)d_in[12];
  const float* b_att = (const float*)d_in[13];
  const float* W_val = (const float*)d_in[14];
  const float* b_val = (const float*)d_in[15];
  const float* W_dec = (const float*)d_in[16];
  const float* b_dec = (const float*)d_in[17];
  const float* W_mu  = (const float*)d_in[18];
  const float* b_mu  = (const float*)d_in[19];
  const float* W_sig = (const float*)d_in[20];
  const float* b_sig = (const float*)d_in[21];
  float* ws = (float*)d_ws;
  float* out = (float*)d_out;

  if (ws_size < (size_t)WS_FLOATS * sizeof(float)) return;

  hipMemsetAsync(ws + OFF_E, 0, (size_t)Bb*Nn*Nn*sizeof(float), stream);
  k_precompute<<<51, 384, 0, stream>>>(W_se, b_se, W_ih, b_ih, W_hh, W_kc, W_qc,
                                       W_vc, W_att, W_dec, W_mu, W_sig, ws);
  k_gru<<<BN/4, 512, 0, stream>>>(x, W_init, b_init, b_hh, ws);
  k_kqv<<<Bb*Tt, 256, 0, stream>>>(ws);
  k_attn<<<Bb*Hh, 1024, 0, stream>>>(ws);
  k_decode<<<BN/4, 384, 0, stream>>>(x, W_hh, b_hh, W_val, b_val, ws);
  k_final<<<Bb*4, 256, 0, stream>>>(b_dec, b_mu, b_sig, b_att, ws, out);
}